// Round 11
// baseline (100.936 us; speedup 1.0000x reference)
//
#include <hip/hip_runtime.h>
#include <hip/hip_bf16.h>
#include <stdint.h>

#define NPB 8192
#define CB 2
#define CC 128
#define HH 4
#define KTOK 4096
#define DH 32
#define NTOK (CB*KTOK)
#define K2C 0.25503402f  /* log2(e)/sqrt(32) */

typedef __attribute__((ext_vector_type(8))) short sh8;
typedef __attribute__((ext_vector_type(4))) float fx4;
typedef __attribute__((ext_vector_type(16))) float fx16;
typedef __attribute__((ext_vector_type(2))) uint32_t ux2;
typedef __attribute__((ext_vector_type(4))) uint32_t ux4;

__device__ inline uint16_t f2bf(float f){
  uint32_t x = __float_as_uint(f);
  return (uint16_t)((x + 0x7FFFu + ((x>>16)&1u)) >> 16);
}
__device__ inline uint32_t pk2(float a, float b){
  return (uint32_t)f2bf(a) | ((uint32_t)f2bf(b) << 16);
}
__device__ inline float fast_exp2(float x){
#if __has_builtin(__builtin_amdgcn_exp2f)
  return __builtin_amdgcn_exp2f(x);
#else
  return exp2f(x);
#endif
}
__device__ inline uint32_t cvtpk1(float a, float b){
  uint32_t u;
  asm("v_cvt_pk_bf16_f32 %0, %1, %2" : "=v"(u) : "v"(a), "v"(b));
  return u;
}
__device__ inline fx4 mfma32(sh8 a, sh8 b, fx4 c){
  return __builtin_amdgcn_mfma_f32_16x16x32_bf16(a, b, c, 0, 0, 0);
}
__device__ inline fx16 mfma32x32(sh8 a, sh8 b, fx16 c){
  return __builtin_amdgcn_mfma_f32_32x32x16_bf16(a, b, c, 0, 0, 0);
}
__device__ inline void gload_lds(const uint16_t* g, uint16_t* l){
  __builtin_amdgcn_global_load_lds(
      (const __attribute__((address_space(1))) uint32_t*)g,
      (__attribute__((address_space(3))) uint32_t*)l,
      16, 0, 0);
}
/* softmax + in-register P->A-frag exchange for one 32x32 S tile (R8/R10-proven) */
__device__ inline void p_frags(const fx16& S, float& lsum, sh8& pa0, sh8& pa1, int hi){
  float e0  = fast_exp2(S[0]),  e1  = fast_exp2(S[1]);
  float e2  = fast_exp2(S[2]),  e3  = fast_exp2(S[3]);
  float e4  = fast_exp2(S[4]),  e5  = fast_exp2(S[5]);
  float e6  = fast_exp2(S[6]),  e7  = fast_exp2(S[7]);
  float e8  = fast_exp2(S[8]),  e9  = fast_exp2(S[9]);
  float e10 = fast_exp2(S[10]), e11 = fast_exp2(S[11]);
  float e12 = fast_exp2(S[12]), e13 = fast_exp2(S[13]);
  float e14 = fast_exp2(S[14]), e15 = fast_exp2(S[15]);
  lsum += (((e0+e1)+(e2+e3)) + ((e4+e5)+(e6+e7)))
        + (((e8+e9)+(e10+e11)) + ((e12+e13)+(e14+e15)));
  uint32_t X0 = cvtpk1(e0,  e1),  X1 = cvtpk1(e2,  e3);
  uint32_t X2 = cvtpk1(e4,  e5),  X3 = cvtpk1(e6,  e7);
  uint32_t X4 = cvtpk1(e8,  e9),  X5 = cvtpk1(e10, e11);
  uint32_t X6 = cvtpk1(e12, e13), X7 = cvtpk1(e14, e15);
  uint32_t t0 = __shfl_xor(hi ? X0 : X2, 32);
  uint32_t t1 = __shfl_xor(hi ? X1 : X3, 32);
  uint32_t t2 = __shfl_xor(hi ? X4 : X6, 32);
  uint32_t t3 = __shfl_xor(hi ? X5 : X7, 32);
  ux4 w0, w1;
  w0.x = hi ? t0 : X0;  w0.y = hi ? t1 : X1;
  w0.z = hi ? X2 : t0;  w0.w = hi ? X3 : t1;
  w1.x = hi ? t2 : X4;  w1.y = hi ? t3 : X5;
  w1.z = hi ? X6 : t2;  w1.w = hi ? X7 : t3;
  pa0 = *(sh8*)&w0;
  pa1 = *(sh8*)&w1;
}

/* ---------------- K0: copy feats -> out (non-selected rows stay) -------- */
__global__ __launch_bounds__(256) void k_copy(const float4* __restrict__ src,
                                              float4* __restrict__ dst, int n4){
  int i = blockIdx.x*256 + threadIdx.x;
  if (i < n4) dst[i] = src[i];
}

/* ---------------- K1: per-row squared L2 norm as sortable u32 ----------- */
__global__ __launch_bounds__(256) void k_norms(const float* __restrict__ feats,
                                               uint32_t* __restrict__ keys){
  int row  = blockIdx.x*4 + (threadIdx.x>>6);
  int lane = threadIdx.x & 63;
  float2 v = *(const float2*)(feats + row*CC + lane*2);
  float s = v.x*v.x + v.y*v.y;
  for (int m=1; m<64; m<<=1) s += __shfl_xor(s, m);
  if (lane == 0) keys[row] = __float_as_uint(s);  // >=0 -> monotone as uint
}

/* ---------------- K2: exact top-4096 selection per batch ---------------- */
__global__ __launch_bounds__(1024) void k_select(const uint32_t* __restrict__ keys,
                                                 int* __restrict__ sel){
  __shared__ uint32_t ka[NPB];
  __shared__ uint32_t hist[16*257];
  __shared__ uint32_t comb[256];
  __shared__ uint32_t sh_prefix, sh_r;
  __shared__ int wsum[17];
  int tid = threadIdx.x, batch = blockIdx.x;
  int wv16 = tid >> 6;
  for (int i = tid; i < NPB; i += 1024) ka[i] = keys[batch*NPB + i];
  if (tid == 0){ sh_prefix = 0u; sh_r = KTOK; }
  __syncthreads();
  for (int pass = 0; pass < 4; ++pass){
    int shift = 24 - 8*pass;
    for (int i = tid; i < 16*257; i += 1024) hist[i] = 0u;
    __syncthreads();
    uint32_t pref = sh_prefix;
    uint32_t r0   = sh_r;
    uint32_t mask = (pass == 0) ? 0u : (0xFFFFFFFFu << (shift + 8));
    uint32_t* myh = &hist[wv16*257];
    for (int e = 0; e < 8; ++e){
      uint32_t k = ka[tid*8 + e];
      if ((k & mask) == pref) atomicAdd(&myh[(k >> shift) & 255], 1u);
    }
    __syncthreads();
    uint32_t h0 = 0;
    if (tid < 256){
      for (int w = 0; w < 16; ++w) h0 += hist[w*257 + tid];
      comb[tid] = h0;
    }
    __syncthreads();
    for (int off = 1; off < 256; off <<= 1){
      uint32_t v = (tid < 256 && tid + off < 256) ? comb[tid + off] : 0u;
      __syncthreads();
      if (tid < 256) comb[tid] += v;
      __syncthreads();
    }
    if (tid < 256){
      uint32_t incl = comb[tid];
      uint32_t Sx   = incl - h0;
      if (Sx < r0 && incl >= r0){
        sh_prefix = pref | ((uint32_t)tid << shift);
        sh_r = r0 - Sx;
      }
    }
    __syncthreads();
  }
  uint32_t T = sh_prefix; int need = (int)sh_r;
  int lgt = 0, leq = 0;
  for (int e = 0; e < 8; ++e){
    uint32_t k = ka[tid*8 + e];
    lgt += (k > T); leq += (k == T);
  }
  int lane = tid & 63, wv = tid >> 6;
  int egt, tgt, eeq;
  {
    __syncthreads();
    int incl = lgt;
    for (int d = 1; d < 64; d <<= 1){ int t = __shfl_up(incl, d); if (lane >= d) incl += t; }
    if (lane == 63) wsum[wv] = incl;
    __syncthreads();
    if (tid == 0){ int run = 0; for (int w = 0; w < 16; ++w){ int t = wsum[w]; wsum[w] = run; run += t; } wsum[16] = run; }
    __syncthreads();
    egt = wsum[wv] + incl - lgt; tgt = wsum[16];
  }
  {
    __syncthreads();
    int incl = leq;
    for (int d = 1; d < 64; d <<= 1){ int t = __shfl_up(incl, d); if (lane >= d) incl += t; }
    if (lane == 63) wsum[wv] = incl;
    __syncthreads();
    if (tid == 0){ int run = 0; for (int w = 0; w < 16; ++w){ int t = wsum[w]; wsum[w] = run; run += t; } }
    __syncthreads();
    eeq = wsum[wv] + incl - leq;
  }
  int chi = tgt, gpos = egt, epos = eeq;
  for (int e = 0; e < 8; ++e){
    int i = tid*8 + e;
    uint32_t k = ka[i];
    if (k > T){ sel[batch*KTOK + (gpos++)] = batch*NPB + i; }
    else if (k == T){ if (epos < need) sel[batch*KTOK + chi + epos] = batch*NPB + i; epos++; }
  }
}

/* ---------------- K3: weights fp32 -> bf16 ------------------------------ */
__global__ __launch_bounds__(256) void k_wconv(const float* __restrict__ wq,
                                               const float* __restrict__ wo,
                                               uint16_t* __restrict__ wqb,
                                               uint16_t* __restrict__ wob){
  int i = blockIdx.x*256 + threadIdx.x;  // 0..65535
  if (i < 3*CC*CC) wqb[i] = f2bf(wq[i]);
  else { int j = i - 3*CC*CC; wob[j] = f2bf(wo[j]); }
}

/* ---------------- K4: gather selected rows to bf16 ---------------------- */
__global__ __launch_bounds__(256) void k_gather(const float* __restrict__ feats,
                                                const int* __restrict__ sel,
                                                uint32_t* __restrict__ xab){
  int t    = blockIdx.x*4 + (threadIdx.x>>6);
  int lane = threadIdx.x & 63;
  int g = sel[t];
  float2 v = *(const float2*)(feats + g*CC + lane*2);
  xab[t*(CC/2) + lane] = pk2(v.x, v.y);
}

/* ---------------- K5: QKV projection GEMM (8192x384x128) ---------------- */
/* Q is pre-scaled by log2(e)/sqrt(Dh) so attention uses exp2 directly.    */
__global__ __launch_bounds__(256) void k_qkv(const uint32_t* __restrict__ xab,
                                             const uint16_t* __restrict__ wqb,
                                             const float* __restrict__ bias,
                                             uint16_t* __restrict__ Qg,
                                             uint16_t* __restrict__ Kg,
                                             uint16_t* __restrict__ Vt){
  int wave = threadIdx.x >> 6, lane = threadIdx.x & 63;
  int l15 = lane & 15, g = lane >> 4;
  int rt = blockIdx.x;               // 512 row tiles
  int ct = blockIdx.y*4 + wave;      // 24 col tiles
  int arow = rt*16 + l15;
  int bcol = ct*16 + l15;
  fx4 acc = {0.f,0.f,0.f,0.f};
  const uint16_t* xb = (const uint16_t*)xab;
#pragma unroll
  for (int kk = 0; kk < 4; ++kk){
    sh8 aF = *(const sh8*)(xb + arow*CC + kk*32 + g*8);
    sh8 bF = *(const sh8*)(wqb + bcol*CC + kk*32 + g*8);
    acc = mfma32(aF, bF, acc);
  }
  int j = bcol;
  float bj = bias[j];
  int tbase = rt*16;
  int b  = tbase >> 12;
  int q0 = (tbase & 4095) + g*4;     // 4 consecutive within-batch slots
  if (j < CC){
    int h = j >> 5, d = j & 31;
    uint16_t* p = Qg + ((b*HH + h)*KTOK + q0)*DH + d;
#pragma unroll
    for (int i = 0; i < 4; ++i) p[i*DH] = f2bf((acc[i] + bj) * K2C);
  } else if (j < 2*CC){
    int jj = j - CC; int h = jj >> 5, d = jj & 31;
    uint16_t* p = Kg + ((b*HH + h)*KTOK + q0)*DH + d;
#pragma unroll
    for (int i = 0; i < 4; ++i) p[i*DH] = f2bf(acc[i] + bj);
  } else {
    int jj = j - 2*CC; int h = jj >> 5, d = jj & 31;
    uint16_t* p = Vt + ((b*HH + h)*DH + d)*KTOK + q0;
    ux2 w; w.x = pk2(acc[0]+bj, acc[1]+bj); w.y = pk2(acc[2]+bj, acc[3]+bj);
    *(ux2*)p = w;
  }
}

/* ---- K6: attention — 64q per wave: K/V frags amortized over 2 S-tiles -- */
/* Block = 8 waves (512 thr) = one 64-q tile (2x32q sub-tiles A,B) x 8
   key-segments of 512. Grid (64,8) = 512 blocks = 2/CU = 16 waves/CU.
   Per iter each wave reads K/V frags ONCE from its private swizzled LDS
   staging (R10-proven layout+swizzle) and feeds BOTH sub-tiles' QK^T and
   PV -> LDS read per S-tile halves; staging traffic halves (half the
   blocks). All math (no-max softmax, cvt_pk, half-exchange) R10-proven.
   Combine: 8 segments x 2 tiles in LDS (staging region reused after
   barrier); wave 0 normalizes and stores both tiles. */
__global__ __launch_bounds__(512, 4) void k_attn(const uint16_t* __restrict__ Qg,
                                                 const uint16_t* __restrict__ Kg,
                                                 const uint16_t* __restrict__ Vtg,
                                                 uint16_t* __restrict__ O){
  __shared__ __align__(16) char lds[67840];
  int tid = threadIdx.x;
  int wv = tid >> 6, lane = tid & 63;
  int l31 = lane & 31, hi = lane >> 5;
  int bh = blockIdx.y;
  int qt = blockIdx.x;                 /* 64 q64-tiles per bh */
  const uint16_t* Qp = Qg  + bh*KTOK*DH;
  const uint16_t* Kp = Kg  + bh*KTOK*DH;
  const uint16_t* Vp = Vtg + bh*DH*KTOK;
  int qA = qt*64 + l31;
  sh8 qF0A = *(const sh8*)(Qp + qA*DH + hi*8);
  sh8 qF1A = *(const sh8*)(Qp + qA*DH + 16 + hi*8);
  sh8 qF0B = *(const sh8*)(Qp + (qA+32)*DH + hi*8);
  sh8 qF1B = *(const sh8*)(Qp + (qA+32)*DH + 16 + hi*8);

  uint16_t* st = (uint16_t*)lds + wv*4096;  /* 8KB/wave: [2buf][K 1024|V 1024] */
  int key0 = wv*512;
  int r16 = lane >> 2;
  int sx  = ((lane & 3) ^ ((r16 >> 1) & 3)) * 8;   /* pre-swizzled source slot */

  /* prologue: stage tile 0 -> buf0 */
  {
    const uint16_t* kg = Kp + key0*DH;
    const uint16_t* vg = Vp + key0;
    gload_lds(kg + r16*DH + sx,        st + 0);
    gload_lds(kg + (16+r16)*DH + sx,   st + 512);
    gload_lds(vg + r16*KTOK + sx,      st + 1024);
    gload_lds(vg + (16+r16)*KTOK + sx, st + 1536);
  }
  asm volatile("s_waitcnt vmcnt(0)" ::: "memory");

  fx16 accA = {0,0,0,0,0,0,0,0,0,0,0,0,0,0,0,0};
  fx16 accB = {0,0,0,0,0,0,0,0,0,0,0,0,0,0,0,0};
  const fx16 z16 = {0,0,0,0,0,0,0,0,0,0,0,0,0,0,0,0};
  float lsA = 0.f, lsB = 0.f;
  int swz = (l31 >> 1) & 3;
  int koff0 = l31*32 + ((hi     ^ swz)*8);
  int koff1 = l31*32 + (((hi+2) ^ swz)*8);

  for (int t = 0; t < 16; ++t){
    int b = t & 1;
    if (t < 15){
      const uint16_t* kg = Kp + (key0 + (t+1)*32)*DH;
      const uint16_t* vg = Vp + key0 + (t+1)*32;
      uint16_t* d = st + (b^1)*2048;
      gload_lds(kg + r16*DH + sx,        d + 0);
      gload_lds(kg + (16+r16)*DH + sx,   d + 512);
      gload_lds(vg + r16*KTOK + sx,      d + 1024);
      gload_lds(vg + (16+r16)*KTOK + sx, d + 1536);
    }
    const uint16_t* bK = st + b*2048;
    const uint16_t* bV = st + b*2048 + 1024;
    sh8 kA0 = *(const sh8*)(bK + koff0);
    sh8 kA1 = *(const sh8*)(bK + koff1);
    sh8 vB0 = *(const sh8*)(bV + koff0);
    sh8 vB1 = *(const sh8*)(bV + koff1);
    fx16 SA = mfma32x32(kA0, qF0A, z16);
    SA = mfma32x32(kA1, qF1A, SA);
    fx16 SB = mfma32x32(kA0, qF0B, z16);
    SB = mfma32x32(kA1, qF1B, SB);
    sh8 paA0, paA1, paB0, paB1;
    p_frags(SA, lsA, paA0, paA1, hi);
    p_frags(SB, lsB, paB0, paB1, hi);
    accA = mfma32x32(paA0, vB0, accA);
    accA = mfma32x32(paA1, vB1, accA);
    accB = mfma32x32(paB0, vB0, accB);
    accB = mfma32x32(paB1, vB1, accB);
    asm volatile("s_waitcnt vmcnt(0)" ::: "memory");
  }

  /* combine 8 segments x 2 tiles; staging region reused after barrier */
  __syncthreads();
  float* cmbA = (float*)lds;                     /* [8][64][16] = 32KB */
  float* cmbB = (float*)(lds + 32768);           /* [8][64][16] = 32KB */
  float* lwp  = (float*)(lds + 65536);           /* [8][2][32] = 2KB   */
  float* ltrA = (float*)(lds + 65536 + 2048);    /* [32]               */
  float* ltrB = (float*)(lds + 65536 + 2048 + 128);
  lsA += __shfl_xor(lsA, 32);
  lsB += __shfl_xor(lsB, 32);
#pragma unroll
  for (int i = 0; i < 16; i += 4){
    fx4 pA = {accA[i], accA[i+1], accA[i+2], accA[i+3]};
    fx4 pB = {accB[i], accB[i+1], accB[i+2], accB[i+3]};
    *(fx4*)&cmbA[(wv*64 + lane)*16 + i] = pA;
    *(fx4*)&cmbB[(wv*64 + lane)*16 + i] = pB;
  }
  if (!hi){ lwp[wv*64 + l31] = lsA; lwp[wv*64 + 32 + l31] = lsB; }
  __syncthreads();
  if (wv == 0){
#pragma unroll
    for (int w = 1; w < 8; ++w){
#pragma unroll
      for (int i = 0; i < 16; i += 4){
        fx4 pA = *(const fx4*)&cmbA[(w*64 + lane)*16 + i];
        fx4 pB = *(const fx4*)&cmbB[(w*64 + lane)*16 + i];
        accA[i] += pA.x; accA[i+1] += pA.y; accA[i+2] += pA.z; accA[i+3] += pA.w;
        accB[i] += pB.x; accB[i+1] += pB.y; accB[i+2] += pB.z; accB[i+3] += pB.w;
      }
    }
    float ltA = 0.f, ltB = 0.f;
#pragma unroll
    for (int w = 0; w < 8; ++w){ ltA += lwp[w*64 + l31]; ltB += lwp[w*64 + 32 + l31]; }
    if (!hi){ ltrA[l31] = ltA; ltrB[l31] = ltB; }
    int bb = bh >> 2, h = bh & 3;
    uint16_t* opA = O + (bb*KTOK + qt*64)*CC + h*DH + l31;
    uint16_t* opB = opA + 32*CC;
    {
      fx4 La = *(const fx4*)&ltrA[4*hi];
      fx4 Lb = *(const fx4*)&ltrA[8+4*hi];
      fx4 Lc = *(const fx4*)&ltrA[16+4*hi];
      fx4 Ld = *(const fx4*)&ltrA[24+4*hi];
      fx4 Ra = {1.f/La.x, 1.f/La.y, 1.f/La.z, 1.f/La.w};
      fx4 Rb = {1.f/Lb.x, 1.f/Lb.y, 1.f/Lb.z, 1.f/Lb.w};
      fx4 Rc = {1.f/Lc.x, 1.f/Lc.y, 1.f/Lc.z, 1.f/Lc.w};
      fx4 Rd = {1.f/Ld.x, 1.f/Ld.y, 1.f/Ld.z, 1.f/Ld.w};
#pragma unroll
      for (int r = 0; r < 16; ++r){
        int qd = (r&3) + 8*(r>>2) + 4*hi;
        float rv = (r<4) ? Ra[r&3] : (r<8) ? Rb[r&3] : (r<12) ? Rc[r&3] : Rd[r&3];
        opA[qd*CC] = f2bf(accA[r] * rv);
      }
    }
    {
      fx4 La = *(const fx4*)&ltrB[4*hi];
      fx4 Lb = *(const fx4*)&ltrB[8+4*hi];
      fx4 Lc = *(const fx4*)&ltrB[16+4*hi];
      fx4 Ld = *(const fx4*)&ltrB[24+4*hi];
      fx4 Ra = {1.f/La.x, 1.f/La.y, 1.f/La.z, 1.f/La.w};
      fx4 Rb = {1.f/Lb.x, 1.f/Lb.y, 1.f/Lb.z, 1.f/Lb.w};
      fx4 Rc = {1.f/Lc.x, 1.f/Lc.y, 1.f/Lc.z, 1.f/Lc.w};
      fx4 Rd = {1.f/Ld.x, 1.f/Ld.y, 1.f/Ld.z, 1.f/Ld.w};
#pragma unroll
      for (int r = 0; r < 16; ++r){
        int qd = (r&3) + 8*(r>>2) + 4*hi;
        float rv = (r<4) ? Ra[r&3] : (r<8) ? Rb[r&3] : (r<12) ? Rc[r&3] : Rd[r&3];
        opB[qd*CC] = f2bf(accB[r] * rv);
      }
    }
  }
}

/* ---------------- K7: out-proj + residual + LayerNorm + scatter --------- */
__global__ __launch_bounds__(256) void k_outln(const uint16_t* __restrict__ O,
                                               const uint16_t* __restrict__ wob,
                                               const float* __restrict__ bo,
                                               const float* __restrict__ feats,
                                               const int* __restrict__ sel,
                                               const float* __restrict__ lnw,
                                               const float* __restrict__ lnb,
                                               float* __restrict__ out){
  __shared__ float red[16][4][2];
  int wave = threadIdx.x >> 6, lane = threadIdx.x & 63;
  int l15 = lane & 15, g = lane >> 4;
  int rt = blockIdx.x;
  int arow = rt*16 + l15;
  int jA = wave*32 + l15, jB = jA + 16;
  fx4 accA = {0,0,0,0}, accB = {0,0,0,0};
#pragma unroll
  for (int kk = 0; kk < 4; ++kk){
    sh8 aF = *(const sh8*)(O   + arow*CC + kk*32 + g*8);
    sh8 b0 = *(const sh8*)(wob + jA*CC   + kk*32 + g*8);
    sh8 b1 = *(const sh8*)(wob + jB*CC   + kk*32 + g*8);
    accA = mfma32(aF, b0, accA);
    accB = mfma32(aF, b1, accB);
  }
  float bjA = bo[jA], bjB = bo[jB];
  float hA[4], hB[4]; int gl[4];
#pragma unroll
  for (int i = 0; i < 4; ++i){
    int r = rt*16 + g*4 + i;
    int grow = sel[r];
    gl[i] = grow;
    hA[i] = accA[i] + bjA + feats[grow*CC + jA];
    hB[i] = accB[i] + bjB + feats[grow*CC + jB];
  }
#pragma unroll
  for (int i = 0; i < 4; ++i){
    float s  = hA[i] + hB[i];
    float s2 = hA[i]*hA[i] + hB[i]*hB[i];
    for (int mk = 1; mk < 16; mk <<= 1){ s += __shfl_xor(s, mk); s2 += __shfl_xor(s2, mk); }
    if (l15 == 0){ red[g*4+i][wave][0] = s; red[g*4+i][wave][1] = s2; }
  }
  __syncthreads();
  float w0 = lnw[jA], w1 = lnw[jB], b0v = lnb[jA], b1v = lnb[jB];
#pragma unroll
  for (int i = 0; i < 4; ++i){
    int rl = g*4 + i;
    float tot  = red[rl][0][0] + red[rl][1][0] + red[rl][2][0] + red[rl][3][0];
    float tot2 = red[rl][0][1] + red[rl][1][1] + red[rl][2][1] + red[rl][3][1];
    float mu  = tot  * (1.f/128.f);
    float var = tot2 * (1.f/128.f) - mu*mu;
    float rs = rsqrtf(var + 1e-5f);
    out[gl[i]*CC + jA] = (hA[i]-mu)*rs*w0 + b0v;
    out[gl[i]*CC + jB] = (hB[i]-mu)*rs*w1 + b1v;
  }
}

extern "C" void kernel_launch(void* const* d_in, const int* in_sizes, int n_in,
                              void* d_out, int out_size, void* d_ws, size_t ws_size,
                              hipStream_t stream){
  const float* feats = (const float*)d_in[0];
  /* d_in[1] = batch_idx (int64) — contiguous equal groups, unused */
  const float* wqkv  = (const float*)d_in[2];
  const float* bqkv  = (const float*)d_in[3];
  const float* wout  = (const float*)d_in[4];
  const float* bout  = (const float*)d_in[5];
  const float* lnw   = (const float*)d_in[6];
  const float* lnb   = (const float*)d_in[7];
  float* out = (float*)d_out;
  char* ws = (char*)d_ws;

  uint32_t* keys = (uint32_t*)(ws + 0);        /* 64KB  */
  int*      sel  = (int*)     (ws + 65536);    /* 32KB  */
  uint16_t* wqb  = (uint16_t*)(ws + 98304);    /* 96KB  */
  uint16_t* wob  = (uint16_t*)(ws + 196608);   /* 32KB  */
  uint32_t* xab  = (uint32_t*)(ws + 229376);   /* 2MB   */
  uint16_t* Qg   = (uint16_t*)(ws + 2326528);  /* 2MB   */
  uint16_t* Kg   = (uint16_t*)(ws + 4423680);  /* 2MB   */
  uint16_t* Vt   = (uint16_t*)(ws + 6520832);  /* 2MB   */
  uint16_t* O    = (uint16_t*)(ws + 8617984);  /* 2MB   */

  hipLaunchKernelGGL(k_copy,   dim3(2048),   dim3(256),  0, stream,
                     (const float4*)feats, (float4*)out, (NPB*CB*CC)/4);
  hipLaunchKernelGGL(k_norms,  dim3(4096),   dim3(256),  0, stream, feats, keys);
  hipLaunchKernelGGL(k_select, dim3(2),      dim3(1024), 0, stream, keys, sel);
  hipLaunchKernelGGL(k_wconv,  dim3(256),    dim3(256),  0, stream, wqkv, wout, wqb, wob);
  hipLaunchKernelGGL(k_gather, dim3(2048),   dim3(256),  0, stream, feats, sel, xab);
  hipLaunchKernelGGL(k_qkv,    dim3(512,6),  dim3(256),  0, stream, xab, wqb, bqkv, Qg, Kg, Vt);
  hipLaunchKernelGGL(k_attn,   dim3(64,8),   dim3(512),  0, stream, Qg, Kg, Vt, O);
  hipLaunchKernelGGL(k_outln,  dim3(512),    dim3(256),  0, stream, O, wob, bout, feats, sel, lnw, lnb, out);
}

// Round 12
// 98.286 us; speedup vs baseline: 1.0270x; 1.0270x over previous
//
#include <hip/hip_runtime.h>
#include <hip/hip_bf16.h>
#include <stdint.h>

#define NPB 8192
#define CB 2
#define CC 128
#define HH 4
#define KTOK 4096
#define DH 32
#define NTOK (CB*KTOK)
#define K2C 0.25503402f  /* log2(e)/sqrt(32) */

typedef __attribute__((ext_vector_type(8))) short sh8;
typedef __attribute__((ext_vector_type(4))) float fx4;
typedef __attribute__((ext_vector_type(16))) float fx16;
typedef __attribute__((ext_vector_type(2))) uint32_t ux2;
typedef __attribute__((ext_vector_type(4))) uint32_t ux4;

__device__ inline uint16_t f2bf(float f){
  uint32_t x = __float_as_uint(f);
  return (uint16_t)((x + 0x7FFFu + ((x>>16)&1u)) >> 16);
}
__device__ inline uint32_t pk2(float a, float b){
  return (uint32_t)f2bf(a) | ((uint32_t)f2bf(b) << 16);
}
__device__ inline float fast_exp2(float x){
#if __has_builtin(__builtin_amdgcn_exp2f)
  return __builtin_amdgcn_exp2f(x);
#else
  return exp2f(x);
#endif
}
__device__ inline uint32_t cvtpk1(float a, float b){
  uint32_t u;
  asm("v_cvt_pk_bf16_f32 %0, %1, %2" : "=v"(u) : "v"(a), "v"(b));
  return u;
}
__device__ inline fx4 mfma32(sh8 a, sh8 b, fx4 c){
  return __builtin_amdgcn_mfma_f32_16x16x32_bf16(a, b, c, 0, 0, 0);
}
__device__ inline fx16 mfma32x32(sh8 a, sh8 b, fx16 c){
  return __builtin_amdgcn_mfma_f32_32x32x16_bf16(a, b, c, 0, 0, 0);
}
__device__ inline void gload_lds(const uint16_t* g, uint16_t* l){
  __builtin_amdgcn_global_load_lds(
      (const __attribute__((address_space(1))) uint32_t*)g,
      (__attribute__((address_space(3))) uint32_t*)l,
      16, 0, 0);
}
/* softmax + in-register P->A-frag exchange for one 32x32 S tile (R8/R10-proven) */
__device__ inline void p_frags(const fx16& S, float& lsum, sh8& pa0, sh8& pa1, int hi){
  float e0  = fast_exp2(S[0]),  e1  = fast_exp2(S[1]);
  float e2  = fast_exp2(S[2]),  e3  = fast_exp2(S[3]);
  float e4  = fast_exp2(S[4]),  e5  = fast_exp2(S[5]);
  float e6  = fast_exp2(S[6]),  e7  = fast_exp2(S[7]);
  float e8  = fast_exp2(S[8]),  e9  = fast_exp2(S[9]);
  float e10 = fast_exp2(S[10]), e11 = fast_exp2(S[11]);
  float e12 = fast_exp2(S[12]), e13 = fast_exp2(S[13]);
  float e14 = fast_exp2(S[14]), e15 = fast_exp2(S[15]);
  lsum += (((e0+e1)+(e2+e3)) + ((e4+e5)+(e6+e7)))
        + (((e8+e9)+(e10+e11)) + ((e12+e13)+(e14+e15)));
  uint32_t X0 = cvtpk1(e0,  e1),  X1 = cvtpk1(e2,  e3);
  uint32_t X2 = cvtpk1(e4,  e5),  X3 = cvtpk1(e6,  e7);
  uint32_t X4 = cvtpk1(e8,  e9),  X5 = cvtpk1(e10, e11);
  uint32_t X6 = cvtpk1(e12, e13), X7 = cvtpk1(e14, e15);
  uint32_t t0 = __shfl_xor(hi ? X0 : X2, 32);
  uint32_t t1 = __shfl_xor(hi ? X1 : X3, 32);
  uint32_t t2 = __shfl_xor(hi ? X4 : X6, 32);
  uint32_t t3 = __shfl_xor(hi ? X5 : X7, 32);
  ux4 w0, w1;
  w0.x = hi ? t0 : X0;  w0.y = hi ? t1 : X1;
  w0.z = hi ? X2 : t0;  w0.w = hi ? X3 : t1;
  w1.x = hi ? t2 : X4;  w1.y = hi ? t3 : X5;
  w1.z = hi ? X6 : t2;  w1.w = hi ? X7 : t3;
  pa0 = *(sh8*)&w0;
  pa1 = *(sh8*)&w1;
}

/* ---------------- K0: copy feats -> out (non-selected rows stay) -------- */
__global__ __launch_bounds__(256) void k_copy(const float4* __restrict__ src,
                                              float4* __restrict__ dst, int n4){
  int i = blockIdx.x*256 + threadIdx.x;
  if (i < n4) dst[i] = src[i];
}

/* ---------------- K1: per-row squared L2 norm as sortable u32 ----------- */
__global__ __launch_bounds__(256) void k_norms(const float* __restrict__ feats,
                                               uint32_t* __restrict__ keys){
  int row  = blockIdx.x*4 + (threadIdx.x>>6);
  int lane = threadIdx.x & 63;
  float2 v = *(const float2*)(feats + row*CC + lane*2);
  float s = v.x*v.x + v.y*v.y;
  for (int m=1; m<64; m<<=1) s += __shfl_xor(s, m);
  if (lane == 0) keys[row] = __float_as_uint(s);  // >=0 -> monotone as uint
}

/* ---------------- K2: exact top-4096 selection per batch ---------------- */
__global__ __launch_bounds__(1024) void k_select(const uint32_t* __restrict__ keys,
                                                 int* __restrict__ sel){
  __shared__ uint32_t ka[NPB];
  __shared__ uint32_t hist[16*257];
  __shared__ uint32_t comb[256];
  __shared__ uint32_t sh_prefix, sh_r;
  __shared__ int wsum[17];
  int tid = threadIdx.x, batch = blockIdx.x;
  int wv16 = tid >> 6;
  for (int i = tid; i < NPB; i += 1024) ka[i] = keys[batch*NPB + i];
  if (tid == 0){ sh_prefix = 0u; sh_r = KTOK; }
  __syncthreads();
  for (int pass = 0; pass < 4; ++pass){
    int shift = 24 - 8*pass;
    for (int i = tid; i < 16*257; i += 1024) hist[i] = 0u;
    __syncthreads();
    uint32_t pref = sh_prefix;
    uint32_t r0   = sh_r;
    uint32_t mask = (pass == 0) ? 0u : (0xFFFFFFFFu << (shift + 8));
    uint32_t* myh = &hist[wv16*257];
    for (int e = 0; e < 8; ++e){
      uint32_t k = ka[tid*8 + e];
      if ((k & mask) == pref) atomicAdd(&myh[(k >> shift) & 255], 1u);
    }
    __syncthreads();
    uint32_t h0 = 0;
    if (tid < 256){
      for (int w = 0; w < 16; ++w) h0 += hist[w*257 + tid];
      comb[tid] = h0;
    }
    __syncthreads();
    for (int off = 1; off < 256; off <<= 1){
      uint32_t v = (tid < 256 && tid + off < 256) ? comb[tid + off] : 0u;
      __syncthreads();
      if (tid < 256) comb[tid] += v;
      __syncthreads();
    }
    if (tid < 256){
      uint32_t incl = comb[tid];
      uint32_t Sx   = incl - h0;
      if (Sx < r0 && incl >= r0){
        sh_prefix = pref | ((uint32_t)tid << shift);
        sh_r = r0 - Sx;
      }
    }
    __syncthreads();
  }
  uint32_t T = sh_prefix; int need = (int)sh_r;
  int lgt = 0, leq = 0;
  for (int e = 0; e < 8; ++e){
    uint32_t k = ka[tid*8 + e];
    lgt += (k > T); leq += (k == T);
  }
  int lane = tid & 63, wv = tid >> 6;
  int egt, tgt, eeq;
  {
    __syncthreads();
    int incl = lgt;
    for (int d = 1; d < 64; d <<= 1){ int t = __shfl_up(incl, d); if (lane >= d) incl += t; }
    if (lane == 63) wsum[wv] = incl;
    __syncthreads();
    if (tid == 0){ int run = 0; for (int w = 0; w < 16; ++w){ int t = wsum[w]; wsum[w] = run; run += t; } wsum[16] = run; }
    __syncthreads();
    egt = wsum[wv] + incl - lgt; tgt = wsum[16];
  }
  {
    __syncthreads();
    int incl = leq;
    for (int d = 1; d < 64; d <<= 1){ int t = __shfl_up(incl, d); if (lane >= d) incl += t; }
    if (lane == 63) wsum[wv] = incl;
    __syncthreads();
    if (tid == 0){ int run = 0; for (int w = 0; w < 16; ++w){ int t = wsum[w]; wsum[w] = run; run += t; } }
    __syncthreads();
    eeq = wsum[wv] + incl - leq;
  }
  int chi = tgt, gpos = egt, epos = eeq;
  for (int e = 0; e < 8; ++e){
    int i = tid*8 + e;
    uint32_t k = ka[i];
    if (k > T){ sel[batch*KTOK + (gpos++)] = batch*NPB + i; }
    else if (k == T){ if (epos < need) sel[batch*KTOK + chi + epos] = batch*NPB + i; epos++; }
  }
}

/* ---------------- K3: weights fp32 -> bf16 ------------------------------ */
__global__ __launch_bounds__(256) void k_wconv(const float* __restrict__ wq,
                                               const float* __restrict__ wo,
                                               uint16_t* __restrict__ wqb,
                                               uint16_t* __restrict__ wob){
  int i = blockIdx.x*256 + threadIdx.x;  // 0..65535
  if (i < 3*CC*CC) wqb[i] = f2bf(wq[i]);
  else { int j = i - 3*CC*CC; wob[j] = f2bf(wo[j]); }
}

/* ---------------- K4: gather selected rows to bf16 ---------------------- */
__global__ __launch_bounds__(256) void k_gather(const float* __restrict__ feats,
                                                const int* __restrict__ sel,
                                                uint32_t* __restrict__ xab){
  int t    = blockIdx.x*4 + (threadIdx.x>>6);
  int lane = threadIdx.x & 63;
  int g = sel[t];
  float2 v = *(const float2*)(feats + g*CC + lane*2);
  xab[t*(CC/2) + lane] = pk2(v.x, v.y);
}

/* ---------------- K5: QKV projection GEMM (8192x384x128) ---------------- */
/* Q is pre-scaled by log2(e)/sqrt(Dh) so attention uses exp2 directly.    */
__global__ __launch_bounds__(256) void k_qkv(const uint32_t* __restrict__ xab,
                                             const uint16_t* __restrict__ wqb,
                                             const float* __restrict__ bias,
                                             uint16_t* __restrict__ Qg,
                                             uint16_t* __restrict__ Kg,
                                             uint16_t* __restrict__ Vt){
  int wave = threadIdx.x >> 6, lane = threadIdx.x & 63;
  int l15 = lane & 15, g = lane >> 4;
  int rt = blockIdx.x;               // 512 row tiles
  int ct = blockIdx.y*4 + wave;      // 24 col tiles
  int arow = rt*16 + l15;
  int bcol = ct*16 + l15;
  fx4 acc = {0.f,0.f,0.f,0.f};
  const uint16_t* xb = (const uint16_t*)xab;
#pragma unroll
  for (int kk = 0; kk < 4; ++kk){
    sh8 aF = *(const sh8*)(xb + arow*CC + kk*32 + g*8);
    sh8 bF = *(const sh8*)(wqb + bcol*CC + kk*32 + g*8);
    acc = mfma32(aF, bF, acc);
  }
  int j = bcol;
  float bj = bias[j];
  int tbase = rt*16;
  int b  = tbase >> 12;
  int q0 = (tbase & 4095) + g*4;     // 4 consecutive within-batch slots
  if (j < CC){
    int h = j >> 5, d = j & 31;
    uint16_t* p = Qg + ((b*HH + h)*KTOK + q0)*DH + d;
#pragma unroll
    for (int i = 0; i < 4; ++i) p[i*DH] = f2bf((acc[i] + bj) * K2C);
  } else if (j < 2*CC){
    int jj = j - CC; int h = jj >> 5, d = jj & 31;
    uint16_t* p = Kg + ((b*HH + h)*KTOK + q0)*DH + d;
#pragma unroll
    for (int i = 0; i < 4; ++i) p[i*DH] = f2bf(acc[i] + bj);
  } else {
    int jj = j - 2*CC; int h = jj >> 5, d = jj & 31;
    uint16_t* p = Vt + ((b*HH + h)*DH + d)*KTOK + q0;
    ux2 w; w.x = pk2(acc[0]+bj, acc[1]+bj); w.y = pk2(acc[2]+bj, acc[3]+bj);
    *(ux2*)p = w;
  }
}

/* ---- K6: attention — 64q/wave, serialized per-tile softmax (no spill) -- */
/* Structure identical to R11 (math verified) with two liveness fixes:
   (1) __launch_bounds__(512) — no min-wave cap boxing the allocator;
   (2) loop body order: QK(A), QK(B) [kA/qF die], then p_frags(A)+PV(A)
       BEFORE p_frags(B)+PV(B) — only one e[16]/X[8] set live at a time.
   K/V frags feed both 32q sub-tiles: LDS reads per S-tile halved vs R10,
   staging traffic halved (512 blocks vs 1024 re-staging the same keys). */
__global__ __launch_bounds__(512) void k_attn(const uint16_t* __restrict__ Qg,
                                              const uint16_t* __restrict__ Kg,
                                              const uint16_t* __restrict__ Vtg,
                                              uint16_t* __restrict__ O){
  __shared__ __align__(16) char lds[67840];
  int tid = threadIdx.x;
  int wv = tid >> 6, lane = tid & 63;
  int l31 = lane & 31, hi = lane >> 5;
  int bh = blockIdx.y;
  int qt = blockIdx.x;                 /* 64 q64-tiles per bh */
  const uint16_t* Qp = Qg  + bh*KTOK*DH;
  const uint16_t* Kp = Kg  + bh*KTOK*DH;
  const uint16_t* Vp = Vtg + bh*DH*KTOK;
  int qA = qt*64 + l31;
  sh8 qF0A = *(const sh8*)(Qp + qA*DH + hi*8);
  sh8 qF1A = *(const sh8*)(Qp + qA*DH + 16 + hi*8);
  sh8 qF0B = *(const sh8*)(Qp + (qA+32)*DH + hi*8);
  sh8 qF1B = *(const sh8*)(Qp + (qA+32)*DH + 16 + hi*8);

  uint16_t* st = (uint16_t*)lds + wv*4096;  /* 8KB/wave: [2buf][K 1024|V 1024] */
  int key0 = wv*512;
  int r16 = lane >> 2;
  int sx  = ((lane & 3) ^ ((r16 >> 1) & 3)) * 8;   /* pre-swizzled source slot */

  /* prologue: stage tile 0 -> buf0 */
  {
    const uint16_t* kg = Kp + key0*DH;
    const uint16_t* vg = Vp + key0;
    gload_lds(kg + r16*DH + sx,        st + 0);
    gload_lds(kg + (16+r16)*DH + sx,   st + 512);
    gload_lds(vg + r16*KTOK + sx,      st + 1024);
    gload_lds(vg + (16+r16)*KTOK + sx, st + 1536);
  }
  asm volatile("s_waitcnt vmcnt(0)" ::: "memory");

  fx16 accA = {0,0,0,0,0,0,0,0,0,0,0,0,0,0,0,0};
  fx16 accB = {0,0,0,0,0,0,0,0,0,0,0,0,0,0,0,0};
  const fx16 z16 = {0,0,0,0,0,0,0,0,0,0,0,0,0,0,0,0};
  float lsA = 0.f, lsB = 0.f;
  int swz = (l31 >> 1) & 3;
  int koff0 = l31*32 + ((hi     ^ swz)*8);
  int koff1 = l31*32 + (((hi+2) ^ swz)*8);

  for (int t = 0; t < 16; ++t){
    int b = t & 1;
    if (t < 15){
      const uint16_t* kg = Kp + (key0 + (t+1)*32)*DH;
      const uint16_t* vg = Vp + key0 + (t+1)*32;
      uint16_t* d = st + (b^1)*2048;
      gload_lds(kg + r16*DH + sx,        d + 0);
      gload_lds(kg + (16+r16)*DH + sx,   d + 512);
      gload_lds(vg + r16*KTOK + sx,      d + 1024);
      gload_lds(vg + (16+r16)*KTOK + sx, d + 1536);
    }
    const uint16_t* bK = st + b*2048;
    const uint16_t* bV = st + b*2048 + 1024;
    sh8 kA0 = *(const sh8*)(bK + koff0);
    sh8 kA1 = *(const sh8*)(bK + koff1);
    sh8 vB0 = *(const sh8*)(bV + koff0);
    sh8 vB1 = *(const sh8*)(bV + koff1);
    fx16 SA = mfma32x32(kA0, qF0A, z16);
    SA = mfma32x32(kA1, qF1A, SA);
    fx16 SB = mfma32x32(kA0, qF0B, z16);
    SB = mfma32x32(kA1, qF1B, SB);
    /* tile A fully consumed before tile B's softmax begins (liveness) */
    {
      sh8 pa0, pa1;
      p_frags(SA, lsA, pa0, pa1, hi);
      accA = mfma32x32(pa0, vB0, accA);
      accA = mfma32x32(pa1, vB1, accA);
    }
    {
      sh8 pb0, pb1;
      p_frags(SB, lsB, pb0, pb1, hi);
      accB = mfma32x32(pb0, vB0, accB);
      accB = mfma32x32(pb1, vB1, accB);
    }
    asm volatile("s_waitcnt vmcnt(0)" ::: "memory");
  }

  /* combine 8 segments x 2 tiles; staging region reused after barrier */
  __syncthreads();
  float* cmbA = (float*)lds;                     /* [8][64][16] = 32KB */
  float* cmbB = (float*)(lds + 32768);           /* [8][64][16] = 32KB */
  float* lwp  = (float*)(lds + 65536);           /* [8][2][32] = 2KB   */
  float* ltrA = (float*)(lds + 65536 + 2048);    /* [32]               */
  float* ltrB = (float*)(lds + 65536 + 2048 + 128);
  lsA += __shfl_xor(lsA, 32);
  lsB += __shfl_xor(lsB, 32);
#pragma unroll
  for (int i = 0; i < 16; i += 4){
    fx4 pA = {accA[i], accA[i+1], accA[i+2], accA[i+3]};
    fx4 pB = {accB[i], accB[i+1], accB[i+2], accB[i+3]};
    *(fx4*)&cmbA[(wv*64 + lane)*16 + i] = pA;
    *(fx4*)&cmbB[(wv*64 + lane)*16 + i] = pB;
  }
  if (!hi){ lwp[wv*64 + l31] = lsA; lwp[wv*64 + 32 + l31] = lsB; }
  __syncthreads();
  if (wv == 0){
#pragma unroll
    for (int w = 1; w < 8; ++w){
#pragma unroll
      for (int i = 0; i < 16; i += 4){
        fx4 pA = *(const fx4*)&cmbA[(w*64 + lane)*16 + i];
        fx4 pB = *(const fx4*)&cmbB[(w*64 + lane)*16 + i];
        accA[i] += pA.x; accA[i+1] += pA.y; accA[i+2] += pA.z; accA[i+3] += pA.w;
        accB[i] += pB.x; accB[i+1] += pB.y; accB[i+2] += pB.z; accB[i+3] += pB.w;
      }
    }
    float ltA = 0.f, ltB = 0.f;
#pragma unroll
    for (int w = 0; w < 8; ++w){ ltA += lwp[w*64 + l31]; ltB += lwp[w*64 + 32 + l31]; }
    if (!hi){ ltrA[l31] = ltA; ltrB[l31] = ltB; }
    int bb = bh >> 2, h = bh & 3;
    uint16_t* opA = O + (bb*KTOK + qt*64)*CC + h*DH + l31;
    uint16_t* opB = opA + 32*CC;
    {
      fx4 La = *(const fx4*)&ltrA[4*hi];
      fx4 Lb = *(const fx4*)&ltrA[8+4*hi];
      fx4 Lc = *(const fx4*)&ltrA[16+4*hi];
      fx4 Ld = *(const fx4*)&ltrA[24+4*hi];
      fx4 Ra = {1.f/La.x, 1.f/La.y, 1.f/La.z, 1.f/La.w};
      fx4 Rb = {1.f/Lb.x, 1.f/Lb.y, 1.f/Lb.z, 1.f/Lb.w};
      fx4 Rc = {1.f/Lc.x, 1.f/Lc.y, 1.f/Lc.z, 1.f/Lc.w};
      fx4 Rd = {1.f/Ld.x, 1.f/Ld.y, 1.f/Ld.z, 1.f/Ld.w};
#pragma unroll
      for (int r = 0; r < 16; ++r){
        int qd = (r&3) + 8*(r>>2) + 4*hi;
        float rv = (r<4) ? Ra[r&3] : (r<8) ? Rb[r&3] : (r<12) ? Rc[r&3] : Rd[r&3];
        opA[qd*CC] = f2bf(accA[r] * rv);
      }
    }
    {
      fx4 La = *(const fx4*)&ltrB[4*hi];
      fx4 Lb = *(const fx4*)&ltrB[8+4*hi];
      fx4 Lc = *(const fx4*)&ltrB[16+4*hi];
      fx4 Ld = *(const fx4*)&ltrB[24+4*hi];
      fx4 Ra = {1.f/La.x, 1.f/La.y, 1.f/La.z, 1.f/La.w};
      fx4 Rb = {1.f/Lb.x, 1.f/Lb.y, 1.f/Lb.z, 1.f/Lb.w};
      fx4 Rc = {1.f/Lc.x, 1.f/Lc.y, 1.f/Lc.z, 1.f/Lc.w};
      fx4 Rd = {1.f/Ld.x, 1.f/Ld.y, 1.f/Ld.z, 1.f/Ld.w};
#pragma unroll
      for (int r = 0; r < 16; ++r){
        int qd = (r&3) + 8*(r>>2) + 4*hi;
        float rv = (r<4) ? Ra[r&3] : (r<8) ? Rb[r&3] : (r<12) ? Rc[r&3] : Rd[r&3];
        opB[qd*CC] = f2bf(accB[r] * rv);
      }
    }
  }
}

/* ---------------- K7: out-proj + residual + LayerNorm + scatter --------- */
__global__ __launch_bounds__(256) void k_outln(const uint16_t* __restrict__ O,
                                               const uint16_t* __restrict__ wob,
                                               const float* __restrict__ bo,
                                               const float* __restrict__ feats,
                                               const int* __restrict__ sel,
                                               const float* __restrict__ lnw,
                                               const float* __restrict__ lnb,
                                               float* __restrict__ out){
  __shared__ float red[16][4][2];
  int wave = threadIdx.x >> 6, lane = threadIdx.x & 63;
  int l15 = lane & 15, g = lane >> 4;
  int rt = blockIdx.x;
  int arow = rt*16 + l15;
  int jA = wave*32 + l15, jB = jA + 16;
  fx4 accA = {0,0,0,0}, accB = {0,0,0,0};
#pragma unroll
  for (int kk = 0; kk < 4; ++kk){
    sh8 aF = *(const sh8*)(O   + arow*CC + kk*32 + g*8);
    sh8 b0 = *(const sh8*)(wob + jA*CC   + kk*32 + g*8);
    sh8 b1 = *(const sh8*)(wob + jB*CC   + kk*32 + g*8);
    accA = mfma32(aF, b0, accA);
    accB = mfma32(aF, b1, accB);
  }
  float bjA = bo[jA], bjB = bo[jB];
  float hA[4], hB[4]; int gl[4];
#pragma unroll
  for (int i = 0; i < 4; ++i){
    int r = rt*16 + g*4 + i;
    int grow = sel[r];
    gl[i] = grow;
    hA[i] = accA[i] + bjA + feats[grow*CC + jA];
    hB[i] = accB[i] + bjB + feats[grow*CC + jB];
  }
#pragma unroll
  for (int i = 0; i < 4; ++i){
    float s  = hA[i] + hB[i];
    float s2 = hA[i]*hA[i] + hB[i]*hB[i];
    for (int mk = 1; mk < 16; mk <<= 1){ s += __shfl_xor(s, mk); s2 += __shfl_xor(s2, mk); }
    if (l15 == 0){ red[g*4+i][wave][0] = s; red[g*4+i][wave][1] = s2; }
  }
  __syncthreads();
  float w0 = lnw[jA], w1 = lnw[jB], b0v = lnb[jA], b1v = lnb[jB];
#pragma unroll
  for (int i = 0; i < 4; ++i){
    int rl = g*4 + i;
    float tot  = red[rl][0][0] + red[rl][1][0] + red[rl][2][0] + red[rl][3][0];
    float tot2 = red[rl][0][1] + red[rl][1][1] + red[rl][2][1] + red[rl][3][1];
    float mu  = tot  * (1.f/128.f);
    float var = tot2 * (1.f/128.f) - mu*mu;
    float rs = rsqrtf(var + 1e-5f);
    out[gl[i]*CC + jA] = (hA[i]-mu)*rs*w0 + b0v;
    out[gl[i]*CC + jB] = (hB[i]-mu)*rs*w1 + b1v;
  }
}

extern "C" void kernel_launch(void* const* d_in, const int* in_sizes, int n_in,
                              void* d_out, int out_size, void* d_ws, size_t ws_size,
                              hipStream_t stream){
  const float* feats = (const float*)d_in[0];
  /* d_in[1] = batch_idx (int64) — contiguous equal groups, unused */
  const float* wqkv  = (const float*)d_in[2];
  const float* bqkv  = (const float*)d_in[3];
  const float* wout  = (const float*)d_in[4];
  const float* bout  = (const float*)d_in[5];
  const float* lnw   = (const float*)d_in[6];
  const float* lnb   = (const float*)d_in[7];
  float* out = (float*)d_out;
  char* ws = (char*)d_ws;

  uint32_t* keys = (uint32_t*)(ws + 0);        /* 64KB  */
  int*      sel  = (int*)     (ws + 65536);    /* 32KB  */
  uint16_t* wqb  = (uint16_t*)(ws + 98304);    /* 96KB  */
  uint16_t* wob  = (uint16_t*)(ws + 196608);   /* 32KB  */
  uint32_t* xab  = (uint32_t*)(ws + 229376);   /* 2MB   */
  uint16_t* Qg   = (uint16_t*)(ws + 2326528);  /* 2MB   */
  uint16_t* Kg   = (uint16_t*)(ws + 4423680);  /* 2MB   */
  uint16_t* Vt   = (uint16_t*)(ws + 6520832);  /* 2MB   */
  uint16_t* O    = (uint16_t*)(ws + 8617984);  /* 2MB   */

  hipLaunchKernelGGL(k_copy,   dim3(2048),   dim3(256),  0, stream,
                     (const float4*)feats, (float4*)out, (NPB*CB*CC)/4);
  hipLaunchKernelGGL(k_norms,  dim3(4096),   dim3(256),  0, stream, feats, keys);
  hipLaunchKernelGGL(k_select, dim3(2),      dim3(1024), 0, stream, keys, sel);
  hipLaunchKernelGGL(k_wconv,  dim3(256),    dim3(256),  0, stream, wqkv, wout, wqb, wob);
  hipLaunchKernelGGL(k_gather, dim3(2048),   dim3(256),  0, stream, feats, sel, xab);
  hipLaunchKernelGGL(k_qkv,    dim3(512,6),  dim3(256),  0, stream, xab, wqb, bqkv, Qg, Kg, Vt);
  hipLaunchKernelGGL(k_attn,   dim3(64,8),   dim3(512),  0, stream, Qg, Kg, Vt, O);
  hipLaunchKernelGGL(k_outln,  dim3(512),    dim3(256),  0, stream, O, wob, bout, feats, sel, lnw, lnb, out);
}

// Round 13
// 88.674 us; speedup vs baseline: 1.1383x; 1.1084x over previous
//
#include <hip/hip_runtime.h>
#include <hip/hip_bf16.h>
#include <stdint.h>

#define NPB 8192
#define CB 2
#define CC 128
#define HH 4
#define KTOK 4096
#define DH 32
#define NTOK (CB*KTOK)
#define K2C 0.25503402f  /* log2(e)/sqrt(32) */

typedef __attribute__((ext_vector_type(8))) short sh8;
typedef __attribute__((ext_vector_type(4))) float fx4;
typedef __attribute__((ext_vector_type(16))) float fx16;
typedef __attribute__((ext_vector_type(2))) uint32_t ux2;
typedef __attribute__((ext_vector_type(4))) uint32_t ux4;

__device__ inline uint16_t f2bf(float f){
  uint32_t x = __float_as_uint(f);
  return (uint16_t)((x + 0x7FFFu + ((x>>16)&1u)) >> 16);
}
__device__ inline uint32_t pk2(float a, float b){
  return (uint32_t)f2bf(a) | ((uint32_t)f2bf(b) << 16);
}
__device__ inline float fast_exp2(float x){
#if __has_builtin(__builtin_amdgcn_exp2f)
  return __builtin_amdgcn_exp2f(x);
#else
  return exp2f(x);
#endif
}
__device__ inline uint32_t cvtpk1(float a, float b){
  uint32_t u;
  asm("v_cvt_pk_bf16_f32 %0, %1, %2" : "=v"(u) : "v"(a), "v"(b));
  return u;
}
/* exchange: a' = {a.lo, b.lo(from partner half)}, b' = {a.hi, b.hi} — see text */
__device__ inline void plswap(uint32_t& a, uint32_t& b){
#if __has_builtin(__builtin_amdgcn_permlane32_swap)
  typedef __attribute__((ext_vector_type(2))) unsigned int u2;
  u2 r = __builtin_amdgcn_permlane32_swap(a, b, false, false);
  a = r.x; b = r.y;
#else
  int hi = (threadIdx.x & 63) >> 5;
  uint32_t t = __shfl_xor(hi ? a : b, 32);
  uint32_t na = hi ? t : a;
  uint32_t nb = hi ? b : t;
  a = na; b = nb;
#endif
}
__device__ inline fx4 mfma32(sh8 a, sh8 b, fx4 c){
  return __builtin_amdgcn_mfma_f32_16x16x32_bf16(a, b, c, 0, 0, 0);
}
__device__ inline fx16 mfma32x32(sh8 a, sh8 b, fx16 c){
  return __builtin_amdgcn_mfma_f32_32x32x16_bf16(a, b, c, 0, 0, 0);
}
__device__ inline void gload_lds(const uint16_t* g, uint16_t* l){
  __builtin_amdgcn_global_load_lds(
      (const __attribute__((address_space(1))) uint32_t*)g,
      (__attribute__((address_space(3))) uint32_t*)l,
      16, 0, 0);
}

/* ------------- K0: copy feats -> out AND per-row sqnorm keys ------------ */
__global__ __launch_bounds__(256) void k_cpnorm(const float* __restrict__ feats,
                                                float* __restrict__ out,
                                                uint32_t* __restrict__ keys){
  int wv = threadIdx.x >> 6, lane = threadIdx.x & 63;
  int row0 = blockIdx.x*16 + wv*4;
#pragma unroll
  for (int r = 0; r < 4; ++r){
    int row = row0 + r;
    float2 v = *(const float2*)(feats + row*CC + lane*2);
    *(float2*)(out + row*CC + lane*2) = v;
    float s = v.x*v.x + v.y*v.y;
    for (int m = 1; m < 64; m <<= 1) s += __shfl_xor(s, m);
    if (lane == 0) keys[row] = __float_as_uint(s);  /* >=0 -> monotone as uint */
  }
}

/* ---------------- K2: exact top-4096 selection per batch ---------------- */
__global__ __launch_bounds__(1024) void k_select(const uint32_t* __restrict__ keys,
                                                 int* __restrict__ sel){
  __shared__ uint32_t ka[NPB];
  __shared__ uint32_t hist[16*257];
  __shared__ uint32_t comb[256];
  __shared__ uint32_t sh_prefix, sh_r;
  __shared__ int wsum[17];
  int tid = threadIdx.x, batch = blockIdx.x;
  int wv16 = tid >> 6;
  for (int i = tid; i < NPB; i += 1024) ka[i] = keys[batch*NPB + i];
  if (tid == 0){ sh_prefix = 0u; sh_r = KTOK; }
  __syncthreads();
  for (int pass = 0; pass < 4; ++pass){
    int shift = 24 - 8*pass;
    for (int i = tid; i < 16*257; i += 1024) hist[i] = 0u;
    __syncthreads();
    uint32_t pref = sh_prefix;
    uint32_t r0   = sh_r;
    uint32_t mask = (pass == 0) ? 0u : (0xFFFFFFFFu << (shift + 8));
    uint32_t* myh = &hist[wv16*257];
    for (int e = 0; e < 8; ++e){
      uint32_t k = ka[tid*8 + e];
      if ((k & mask) == pref) atomicAdd(&myh[(k >> shift) & 255], 1u);
    }
    __syncthreads();
    uint32_t h0 = 0;
    if (tid < 256){
      for (int w = 0; w < 16; ++w) h0 += hist[w*257 + tid];
      comb[tid] = h0;
    }
    __syncthreads();
    for (int off = 1; off < 256; off <<= 1){
      uint32_t v = (tid < 256 && tid + off < 256) ? comb[tid + off] : 0u;
      __syncthreads();
      if (tid < 256) comb[tid] += v;
      __syncthreads();
    }
    if (tid < 256){
      uint32_t incl = comb[tid];
      uint32_t Sx   = incl - h0;
      if (Sx < r0 && incl >= r0){
        sh_prefix = pref | ((uint32_t)tid << shift);
        sh_r = r0 - Sx;
      }
    }
    __syncthreads();
  }
  uint32_t T = sh_prefix; int need = (int)sh_r;
  int lgt = 0, leq = 0;
  for (int e = 0; e < 8; ++e){
    uint32_t k = ka[tid*8 + e];
    lgt += (k > T); leq += (k == T);
  }
  int lane = tid & 63, wv = tid >> 6;
  int egt, tgt, eeq;
  {
    __syncthreads();
    int incl = lgt;
    for (int d = 1; d < 64; d <<= 1){ int t = __shfl_up(incl, d); if (lane >= d) incl += t; }
    if (lane == 63) wsum[wv] = incl;
    __syncthreads();
    if (tid == 0){ int run = 0; for (int w = 0; w < 16; ++w){ int t = wsum[w]; wsum[w] = run; run += t; } wsum[16] = run; }
    __syncthreads();
    egt = wsum[wv] + incl - lgt; tgt = wsum[16];
  }
  {
    __syncthreads();
    int incl = leq;
    for (int d = 1; d < 64; d <<= 1){ int t = __shfl_up(incl, d); if (lane >= d) incl += t; }
    if (lane == 63) wsum[wv] = incl;
    __syncthreads();
    if (tid == 0){ int run = 0; for (int w = 0; w < 16; ++w){ int t = wsum[w]; wsum[w] = run; run += t; } }
    __syncthreads();
    eeq = wsum[wv] + incl - leq;
  }
  int chi = tgt, gpos = egt, epos = eeq;
  for (int e = 0; e < 8; ++e){
    int i = tid*8 + e;
    uint32_t k = ka[i];
    if (k > T){ sel[batch*KTOK + (gpos++)] = batch*NPB + i; }
    else if (k == T){ if (epos < need) sel[batch*KTOK + chi + epos] = batch*NPB + i; epos++; }
  }
}

/* ---------------- K3: weights fp32 -> bf16 ------------------------------ */
__global__ __launch_bounds__(256) void k_wconv(const float* __restrict__ wq,
                                               const float* __restrict__ wo,
                                               uint16_t* __restrict__ wqb,
                                               uint16_t* __restrict__ wob){
  int i = blockIdx.x*256 + threadIdx.x;  // 0..65535
  if (i < 3*CC*CC) wqb[i] = f2bf(wq[i]);
  else { int j = i - 3*CC*CC; wob[j] = f2bf(wo[j]); }
}

/* ---------------- K4: gather selected rows to bf16 ---------------------- */
__global__ __launch_bounds__(256) void k_gather(const float* __restrict__ feats,
                                                const int* __restrict__ sel,
                                                uint32_t* __restrict__ xab){
  int t    = blockIdx.x*4 + (threadIdx.x>>6);
  int lane = threadIdx.x & 63;
  int g = sel[t];
  float2 v = *(const float2*)(feats + g*CC + lane*2);
  xab[t*(CC/2) + lane] = pk2(v.x, v.y);
}

/* ---------------- K5: QKV projection GEMM (8192x384x128) ---------------- */
/* Q is pre-scaled by log2(e)/sqrt(Dh) so attention uses exp2 directly.    */
__global__ __launch_bounds__(256) void k_qkv(const uint32_t* __restrict__ xab,
                                             const uint16_t* __restrict__ wqb,
                                             const float* __restrict__ bias,
                                             uint16_t* __restrict__ Qg,
                                             uint16_t* __restrict__ Kg,
                                             uint16_t* __restrict__ Vt){
  int wave = threadIdx.x >> 6, lane = threadIdx.x & 63;
  int l15 = lane & 15, g = lane >> 4;
  int rt = blockIdx.x;               // 512 row tiles
  int ct = blockIdx.y*4 + wave;      // 24 col tiles
  int arow = rt*16 + l15;
  int bcol = ct*16 + l15;
  fx4 acc = {0.f,0.f,0.f,0.f};
  const uint16_t* xb = (const uint16_t*)xab;
#pragma unroll
  for (int kk = 0; kk < 4; ++kk){
    sh8 aF = *(const sh8*)(xb + arow*CC + kk*32 + g*8);
    sh8 bF = *(const sh8*)(wqb + bcol*CC + kk*32 + g*8);
    acc = mfma32(aF, bF, acc);
  }
  int j = bcol;
  float bj = bias[j];
  int tbase = rt*16;
  int b  = tbase >> 12;
  int q0 = (tbase & 4095) + g*4;     // 4 consecutive within-batch slots
  if (j < CC){
    int h = j >> 5, d = j & 31;
    uint16_t* p = Qg + ((b*HH + h)*KTOK + q0)*DH + d;
#pragma unroll
    for (int i = 0; i < 4; ++i) p[i*DH] = f2bf((acc[i] + bj) * K2C);
  } else if (j < 2*CC){
    int jj = j - CC; int h = jj >> 5, d = jj & 31;
    uint16_t* p = Kg + ((b*HH + h)*KTOK + q0)*DH + d;
#pragma unroll
    for (int i = 0; i < 4; ++i) p[i*DH] = f2bf(acc[i] + bj);
  } else {
    int jj = j - 2*CC; int h = jj >> 5, d = jj & 31;
    uint16_t* p = Vt + ((b*HH + h)*DH + d)*KTOK + q0;
    ux2 w; w.x = pk2(acc[0]+bj, acc[1]+bj); w.y = pk2(acc[2]+bj, acc[3]+bj);
    *(ux2*)p = w;
  }
}

/* ---- K6: attention — R10 structure + permlane32_swap P-exchange -------- */
/* Identical to R10 (proven 44us: wave-private swizzled staging, conflict-
   free slot^((row>>1)&3) swizzle, 32x32 swapped-QK, in-register P) except
   the half-exchange uses v_permlane32_swap_b32: (X0',X2')=swap(X0,X2)
   reproduces {hi?t0:X0, hi?X2:t0} exactly (derived element-wise), removing
   4 shfl + ~16 cndmask per S-tile. */
__global__ __launch_bounds__(256, 4) void k_attn(const uint16_t* __restrict__ Qg,
                                                 const uint16_t* __restrict__ Kg,
                                                 const uint16_t* __restrict__ Vtg,
                                                 uint16_t* __restrict__ O){
  __shared__ __align__(16) char lds[32768];
  int tid = threadIdx.x;
  int wv = tid >> 6, lane = tid & 63;
  int l31 = lane & 31, hi = lane >> 5;
  int bh = blockIdx.y;
  int qt = blockIdx.x;                 /* 128 q32-tiles per bh */
  const uint16_t* Qp = Qg  + bh*KTOK*DH;
  const uint16_t* Kp = Kg  + bh*KTOK*DH;
  const uint16_t* Vp = Vtg + bh*DH*KTOK;
  int q = qt*32 + l31;
  sh8 qF0 = *(const sh8*)(Qp + q*DH + hi*8);        /* B: col=q, k=dh 0..15  */
  sh8 qF1 = *(const sh8*)(Qp + q*DH + 16 + hi*8);   /* B: col=q, k=dh 16..31 */

  uint16_t* st = (uint16_t*)lds + wv*4096;  /* 8KB/wave: [2 buf][K 1024 | V 1024] elems */
  int key0 = wv*1024;
  int r16 = lane >> 2;
  int sx  = ((lane & 3) ^ ((r16 >> 1) & 3)) * 8;   /* pre-swizzled source slot */

  /* prologue: stage tile 0 -> buf0 */
  {
    const uint16_t* kg = Kp + key0*DH;
    const uint16_t* vg = Vp + key0;
    gload_lds(kg + r16*DH + sx,        st + 0);
    gload_lds(kg + (16+r16)*DH + sx,   st + 512);
    gload_lds(vg + r16*KTOK + sx,      st + 1024);
    gload_lds(vg + (16+r16)*KTOK + sx, st + 1536);
  }
  asm volatile("s_waitcnt vmcnt(0)" ::: "memory");

  fx16 acc = {0,0,0,0,0,0,0,0,0,0,0,0,0,0,0,0};
  const fx16 z16 = {0,0,0,0,0,0,0,0,0,0,0,0,0,0,0,0};
  float lsum = 0.f;
  int swz = (l31 >> 1) & 3;
  int koff0 = l31*32 + ((hi     ^ swz)*8);
  int koff1 = l31*32 + (((hi+2) ^ swz)*8);
  int voff0 = l31*32 + ((hi     ^ swz)*8);
  int voff1 = l31*32 + (((hi+2) ^ swz)*8);

  for (int t = 0; t < 32; ++t){
    int b = t & 1;
    if (t < 31){
      const uint16_t* kg = Kp + (key0 + (t+1)*32)*DH;
      const uint16_t* vg = Vp + key0 + (t+1)*32;
      uint16_t* d = st + (b^1)*2048;
      gload_lds(kg + r16*DH + sx,        d + 0);
      gload_lds(kg + (16+r16)*DH + sx,   d + 512);
      gload_lds(vg + r16*KTOK + sx,      d + 1024);
      gload_lds(vg + (16+r16)*KTOK + sx, d + 1536);
    }
    const uint16_t* bK = st + b*2048;
    const uint16_t* bV = st + b*2048 + 1024;
    sh8 kA0 = *(const sh8*)(bK + koff0);
    sh8 kA1 = *(const sh8*)(bK + koff1);
    fx16 S = mfma32x32(kA0, qF0, z16);
    S = mfma32x32(kA1, qF1, S);
    /* lane holds S for q=l31, keys crow(r,hi)=(r&3)+8*(r>>2)+4*hi */
    float e[16];
#pragma unroll
    for (int r = 0; r < 16; ++r) e[r] = fast_exp2(S[r]);
    float ls = 0.f;
#pragma unroll
    for (int r = 0; r < 16; ++r) ls += e[r];
    lsum += ls;
    uint32_t X0 = cvtpk1(e[0], e[1]),   X1 = cvtpk1(e[2], e[3]);
    uint32_t X2 = cvtpk1(e[4], e[5]),   X3 = cvtpk1(e[6], e[7]);
    uint32_t X4 = cvtpk1(e[8], e[9]),   X5 = cvtpk1(e[10], e[11]);
    uint32_t X6 = cvtpk1(e[12], e[13]), X7 = cvtpk1(e[14], e[15]);
    /* half-exchange via permlane32_swap (equiv. to R10's cndmask net) */
    plswap(X0, X2); plswap(X1, X3);
    plswap(X4, X6); plswap(X5, X7);
    ux4 w0, w1;
    w0.x = X0; w0.y = X1; w0.z = X2; w0.w = X3;
    w1.x = X4; w1.y = X5; w1.z = X6; w1.w = X7;
    sh8 pa0 = *(sh8*)&w0;   /* A: row=q, k=keys 0..15 of tile  */
    sh8 pa1 = *(sh8*)&w1;   /* A: row=q, k=keys 16..31 of tile */
    sh8 vB0 = *(const sh8*)(bV + voff0);   /* B: col=dh, k=keys 0..15  */
    sh8 vB1 = *(const sh8*)(bV + voff1);   /* B: col=dh, k=keys 16..31 */
    acc = mfma32x32(pa0, vB0, acc);
    acc = mfma32x32(pa1, vB1, acc);
    asm volatile("s_waitcnt vmcnt(0)" ::: "memory");
  }

  /* combine 4 segments; reuse lds (all waves past their loops after barrier) */
  __syncthreads();
  float* cmb = (float*)lds;                    /* [4][64][16] f32 = 16KB */
  float* lwp = (float*)(lds + 16384);          /* [4][32] f32            */
  float* ltr = (float*)(lds + 16384 + 512);    /* [32] f32               */
  lsum += __shfl_xor(lsum, 32);                /* full-segment l for q=l31 */
#pragma unroll
  for (int i = 0; i < 16; i += 4){
    fx4 p = {acc[i], acc[i+1], acc[i+2], acc[i+3]};
    *(fx4*)&cmb[(wv*64 + lane)*16 + i] = p;
  }
  if (!hi) lwp[wv*32 + l31] = lsum;
  __syncthreads();
  if (wv == 0){
#pragma unroll
    for (int w = 1; w < 4; ++w){
#pragma unroll
      for (int i = 0; i < 16; i += 4){
        fx4 p = *(const fx4*)&cmb[(w*64 + lane)*16 + i];
        acc[i] += p.x; acc[i+1] += p.y; acc[i+2] += p.z; acc[i+3] += p.w;
      }
    }
    float lt = (lwp[l31] + lwp[32+l31]) + (lwp[64+l31] + lwp[96+l31]);
    if (!hi) ltr[l31] = lt;
    fx4 La = *(const fx4*)&ltr[4*hi];
    fx4 Lb = *(const fx4*)&ltr[8+4*hi];
    fx4 Lc = *(const fx4*)&ltr[16+4*hi];
    fx4 Ld = *(const fx4*)&ltr[24+4*hi];
    fx4 Ra = {1.f/La.x, 1.f/La.y, 1.f/La.z, 1.f/La.w};
    fx4 Rb = {1.f/Lb.x, 1.f/Lb.y, 1.f/Lb.z, 1.f/Lb.w};
    fx4 Rc = {1.f/Lc.x, 1.f/Lc.y, 1.f/Lc.z, 1.f/Lc.w};
    fx4 Rd = {1.f/Ld.x, 1.f/Ld.y, 1.f/Ld.z, 1.f/Ld.w};
    int bb = bh >> 2, h = bh & 3;
    uint16_t* op = O + (bb*KTOK + qt*32)*CC + h*DH + l31;
#pragma unroll
    for (int r = 0; r < 16; ++r){
      int qd = (r&3) + 8*(r>>2) + 4*hi;
      float rv = (r<4) ? Ra[r&3] : (r<8) ? Rb[r&3] : (r<12) ? Rc[r&3] : Rd[r&3];
      op[qd*CC] = f2bf(acc[r] * rv);
    }
  }
}

/* ---------------- K7: out-proj + residual + LayerNorm + scatter --------- */
__global__ __launch_bounds__(256) void k_outln(const uint16_t* __restrict__ O,
                                               const uint16_t* __restrict__ wob,
                                               const float* __restrict__ bo,
                                               const float* __restrict__ feats,
                                               const int* __restrict__ sel,
                                               const float* __restrict__ lnw,
                                               const float* __restrict__ lnb,
                                               float* __restrict__ out){
  __shared__ float red[16][4][2];
  int wave = threadIdx.x >> 6, lane = threadIdx.x & 63;
  int l15 = lane & 15, g = lane >> 4;
  int rt = blockIdx.x;
  int arow = rt*16 + l15;
  int jA = wave*32 + l15, jB = jA + 16;
  fx4 accA = {0,0,0,0}, accB = {0,0,0,0};
#pragma unroll
  for (int kk = 0; kk < 4; ++kk){
    sh8 aF = *(const sh8*)(O   + arow*CC + kk*32 + g*8);
    sh8 b0 = *(const sh8*)(wob + jA*CC   + kk*32 + g*8);
    sh8 b1 = *(const sh8*)(wob + jB*CC   + kk*32 + g*8);
    accA = mfma32(aF, b0, accA);
    accB = mfma32(aF, b1, accB);
  }
  float bjA = bo[jA], bjB = bo[jB];
  float hA[4], hB[4]; int gl[4];
#pragma unroll
  for (int i = 0; i < 4; ++i){
    int r = rt*16 + g*4 + i;
    int grow = sel[r];
    gl[i] = grow;
    hA[i] = accA[i] + bjA + feats[grow*CC + jA];
    hB[i] = accB[i] + bjB + feats[grow*CC + jB];
  }
#pragma unroll
  for (int i = 0; i < 4; ++i){
    float s  = hA[i] + hB[i];
    float s2 = hA[i]*hA[i] + hB[i]*hB[i];
    for (int mk = 1; mk < 16; mk <<= 1){ s += __shfl_xor(s, mk); s2 += __shfl_xor(s2, mk); }
    if (l15 == 0){ red[g*4+i][wave][0] = s; red[g*4+i][wave][1] = s2; }
  }
  __syncthreads();
  float w0 = lnw[jA], w1 = lnw[jB], b0v = lnb[jA], b1v = lnb[jB];
#pragma unroll
  for (int i = 0; i < 4; ++i){
    int rl = g*4 + i;
    float tot  = red[rl][0][0] + red[rl][1][0] + red[rl][2][0] + red[rl][3][0];
    float tot2 = red[rl][0][1] + red[rl][1][1] + red[rl][2][1] + red[rl][3][1];
    float mu  = tot  * (1.f/128.f);
    float var = tot2 * (1.f/128.f) - mu*mu;
    float rs = rsqrtf(var + 1e-5f);
    out[gl[i]*CC + jA] = (hA[i]-mu)*rs*w0 + b0v;
    out[gl[i]*CC + jB] = (hB[i]-mu)*rs*w1 + b1v;
  }
}

extern "C" void kernel_launch(void* const* d_in, const int* in_sizes, int n_in,
                              void* d_out, int out_size, void* d_ws, size_t ws_size,
                              hipStream_t stream){
  const float* feats = (const float*)d_in[0];
  /* d_in[1] = batch_idx (int64) — contiguous equal groups, unused */
  const float* wqkv  = (const float*)d_in[2];
  const float* bqkv  = (const float*)d_in[3];
  const float* wout  = (const float*)d_in[4];
  const float* bout  = (const float*)d_in[5];
  const float* lnw   = (const float*)d_in[6];
  const float* lnb   = (const float*)d_in[7];
  float* out = (float*)d_out;
  char* ws = (char*)d_ws;

  uint32_t* keys = (uint32_t*)(ws + 0);        /* 64KB  */
  int*      sel  = (int*)     (ws + 65536);    /* 32KB  */
  uint16_t* wqb  = (uint16_t*)(ws + 98304);    /* 96KB  */
  uint16_t* wob  = (uint16_t*)(ws + 196608);   /* 32KB  */
  uint32_t* xab  = (uint32_t*)(ws + 229376);   /* 2MB   */
  uint16_t* Qg   = (uint16_t*)(ws + 2326528);  /* 2MB   */
  uint16_t* Kg   = (uint16_t*)(ws + 4423680);  /* 2MB   */
  uint16_t* Vt   = (uint16_t*)(ws + 6520832);  /* 2MB   */
  uint16_t* O    = (uint16_t*)(ws + 8617984);  /* 2MB   */

  hipLaunchKernelGGL(k_cpnorm, dim3(1024),   dim3(256),  0, stream, feats, out, keys);
  hipLaunchKernelGGL(k_select, dim3(2),      dim3(1024), 0, stream, keys, sel);
  hipLaunchKernelGGL(k_wconv,  dim3(256),    dim3(256),  0, stream, wqkv, wout, wqb, wob);
  hipLaunchKernelGGL(k_gather, dim3(2048),   dim3(256),  0, stream, feats, sel, xab);
  hipLaunchKernelGGL(k_qkv,    dim3(512,6),  dim3(256),  0, stream, xab, wqb, bqkv, Qg, Kg, Vt);
  hipLaunchKernelGGL(k_attn,   dim3(128,8),  dim3(256),  0, stream, Qg, Kg, Vt, O);
  hipLaunchKernelGGL(k_outln,  dim3(512),    dim3(256),  0, stream, O, wob, bout, feats, sel, lnw, lnb, out);
}

// Round 14
// 85.079 us; speedup vs baseline: 1.1864x; 1.0423x over previous
//
#include <hip/hip_runtime.h>
#include <hip/hip_bf16.h>
#include <stdint.h>

#define NPB 8192
#define CB 2
#define CC 128
#define HH 4
#define KTOK 4096
#define DH 32
#define NTOK (CB*KTOK)
#define K2C 0.25503402f  /* log2(e)/sqrt(32) */

typedef __attribute__((ext_vector_type(8))) short sh8;
typedef __attribute__((ext_vector_type(4))) float fx4;
typedef __attribute__((ext_vector_type(16))) float fx16;
typedef __attribute__((ext_vector_type(2))) uint32_t ux2;
typedef __attribute__((ext_vector_type(4))) uint32_t ux4;

__device__ inline uint16_t f2bf(float f){
  uint32_t x = __float_as_uint(f);
  return (uint16_t)((x + 0x7FFFu + ((x>>16)&1u)) >> 16);
}
__device__ inline uint32_t pk2(float a, float b){
  return (uint32_t)f2bf(a) | ((uint32_t)f2bf(b) << 16);
}
__device__ inline float fast_exp2(float x){
#if __has_builtin(__builtin_amdgcn_exp2f)
  return __builtin_amdgcn_exp2f(x);
#else
  return exp2f(x);
#endif
}
__device__ inline uint32_t cvtpk1(float a, float b){
  uint32_t u;
  asm("v_cvt_pk_bf16_f32 %0, %1, %2" : "=v"(u) : "v"(a), "v"(b));
  return u;
}
/* exchange halves across lane<32/lane>=32 (R13-proven) */
__device__ inline void plswap(uint32_t& a, uint32_t& b){
#if __has_builtin(__builtin_amdgcn_permlane32_swap)
  typedef __attribute__((ext_vector_type(2))) unsigned int u2;
  u2 r = __builtin_amdgcn_permlane32_swap(a, b, false, false);
  a = r.x; b = r.y;
#else
  int hi = (threadIdx.x & 63) >> 5;
  uint32_t t = __shfl_xor(hi ? a : b, 32);
  uint32_t na = hi ? t : a;
  uint32_t nb = hi ? b : t;
  a = na; b = nb;
#endif
}
__device__ inline fx4 mfma32(sh8 a, sh8 b, fx4 c){
  return __builtin_amdgcn_mfma_f32_16x16x32_bf16(a, b, c, 0, 0, 0);
}
__device__ inline fx16 mfma32x32(sh8 a, sh8 b, fx16 c){
  return __builtin_amdgcn_mfma_f32_32x32x16_bf16(a, b, c, 0, 0, 0);
}
__device__ inline void gload_lds(const uint16_t* g, uint16_t* l){
  __builtin_amdgcn_global_load_lds(
      (const __attribute__((address_space(1))) uint32_t*)g,
      (__attribute__((address_space(3))) uint32_t*)l,
      16, 0, 0);
}

/* -------- K0: copy feats -> out + sqnorm keys + weight conversion ------- */
__global__ __launch_bounds__(256) void k_cpnw(const float* __restrict__ feats,
                                              float* __restrict__ out,
                                              uint32_t* __restrict__ keys,
                                              const float* __restrict__ wq,
                                              const float* __restrict__ wo,
                                              uint16_t* __restrict__ wqb,
                                              uint16_t* __restrict__ wob){
  int bx = blockIdx.x;
  if (bx < 1024){
    int wv = threadIdx.x >> 6, lane = threadIdx.x & 63;
    int row0 = bx*16 + wv*4;
#pragma unroll
    for (int r = 0; r < 4; ++r){
      int row = row0 + r;
      float2 v = *(const float2*)(feats + row*CC + lane*2);
      *(float2*)(out + row*CC + lane*2) = v;
      float s = v.x*v.x + v.y*v.y;
      for (int m = 1; m < 64; m <<= 1) s += __shfl_xor(s, m);
      if (lane == 0) keys[row] = __float_as_uint(s);
    }
  } else {
    int i = (bx - 1024)*256 + threadIdx.x;   /* 0..65535 */
    if (i < 3*CC*CC) wqb[i] = f2bf(wq[i]);
    else { int j = i - 3*CC*CC; wob[j] = f2bf(wo[j]); }
  }
}

/* ---------------- K2: exact top-4096 selection per batch ---------------- */
__global__ __launch_bounds__(1024) void k_select(const uint32_t* __restrict__ keys,
                                                 int* __restrict__ sel){
  __shared__ uint32_t ka[NPB];
  __shared__ uint32_t hist[16*257];
  __shared__ uint32_t comb[256];
  __shared__ uint32_t sh_prefix, sh_r;
  __shared__ int wsum[17];
  int tid = threadIdx.x, batch = blockIdx.x;
  int wv16 = tid >> 6;
  for (int i = tid; i < NPB; i += 1024) ka[i] = keys[batch*NPB + i];
  if (tid == 0){ sh_prefix = 0u; sh_r = KTOK; }
  __syncthreads();
  for (int pass = 0; pass < 4; ++pass){
    int shift = 24 - 8*pass;
    for (int i = tid; i < 16*257; i += 1024) hist[i] = 0u;
    __syncthreads();
    uint32_t pref = sh_prefix;
    uint32_t r0   = sh_r;
    uint32_t mask = (pass == 0) ? 0u : (0xFFFFFFFFu << (shift + 8));
    uint32_t* myh = &hist[wv16*257];
    for (int e = 0; e < 8; ++e){
      uint32_t k = ka[tid*8 + e];
      if ((k & mask) == pref) atomicAdd(&myh[(k >> shift) & 255], 1u);
    }
    __syncthreads();
    uint32_t h0 = 0;
    if (tid < 256){
      for (int w = 0; w < 16; ++w) h0 += hist[w*257 + tid];
      comb[tid] = h0;
    }
    __syncthreads();
    for (int off = 1; off < 256; off <<= 1){
      uint32_t v = (tid < 256 && tid + off < 256) ? comb[tid + off] : 0u;
      __syncthreads();
      if (tid < 256) comb[tid] += v;
      __syncthreads();
    }
    if (tid < 256){
      uint32_t incl = comb[tid];
      uint32_t Sx   = incl - h0;
      if (Sx < r0 && incl >= r0){
        sh_prefix = pref | ((uint32_t)tid << shift);
        sh_r = r0 - Sx;
      }
    }
    __syncthreads();
  }
  uint32_t T = sh_prefix; int need = (int)sh_r;
  int lgt = 0, leq = 0;
  for (int e = 0; e < 8; ++e){
    uint32_t k = ka[tid*8 + e];
    lgt += (k > T); leq += (k == T);
  }
  int lane = tid & 63, wv = tid >> 6;
  int egt, tgt, eeq;
  {
    __syncthreads();
    int incl = lgt;
    for (int d = 1; d < 64; d <<= 1){ int t = __shfl_up(incl, d); if (lane >= d) incl += t; }
    if (lane == 63) wsum[wv] = incl;
    __syncthreads();
    if (tid == 0){ int run = 0; for (int w = 0; w < 16; ++w){ int t = wsum[w]; wsum[w] = run; run += t; } wsum[16] = run; }
    __syncthreads();
    egt = wsum[wv] + incl - lgt; tgt = wsum[16];
  }
  {
    __syncthreads();
    int incl = leq;
    for (int d = 1; d < 64; d <<= 1){ int t = __shfl_up(incl, d); if (lane >= d) incl += t; }
    if (lane == 63) wsum[wv] = incl;
    __syncthreads();
    if (tid == 0){ int run = 0; for (int w = 0; w < 16; ++w){ int t = wsum[w]; wsum[w] = run; run += t; } }
    __syncthreads();
    eeq = wsum[wv] + incl - leq;
  }
  int chi = tgt, gpos = egt, epos = eeq;
  for (int e = 0; e < 8; ++e){
    int i = tid*8 + e;
    uint32_t k = ka[i];
    if (k > T){ sel[batch*KTOK + (gpos++)] = batch*NPB + i; }
    else if (k == T){ if (epos < need) sel[batch*KTOK + chi + epos] = batch*NPB + i; epos++; }
  }
}

/* ---------------- K4: gather selected rows to bf16 ---------------------- */
__global__ __launch_bounds__(256) void k_gather(const float* __restrict__ feats,
                                                const int* __restrict__ sel,
                                                uint32_t* __restrict__ xab){
  int t    = blockIdx.x*4 + (threadIdx.x>>6);
  int lane = threadIdx.x & 63;
  int g = sel[t];
  float2 v = *(const float2*)(feats + g*CC + lane*2);
  xab[t*(CC/2) + lane] = pk2(v.x, v.y);
}

/* ---------------- K5: QKV projection GEMM (8192x384x128) ---------------- */
/* Q is pre-scaled by log2(e)/sqrt(Dh) so attention uses exp2 directly.    */
__global__ __launch_bounds__(256) void k_qkv(const uint32_t* __restrict__ xab,
                                             const uint16_t* __restrict__ wqb,
                                             const float* __restrict__ bias,
                                             uint16_t* __restrict__ Qg,
                                             uint16_t* __restrict__ Kg,
                                             uint16_t* __restrict__ Vt){
  int wave = threadIdx.x >> 6, lane = threadIdx.x & 63;
  int l15 = lane & 15, g = lane >> 4;
  int rt = blockIdx.x;               // 512 row tiles
  int ct = blockIdx.y*4 + wave;      // 24 col tiles
  int arow = rt*16 + l15;
  int bcol = ct*16 + l15;
  fx4 acc = {0.f,0.f,0.f,0.f};
  const uint16_t* xb = (const uint16_t*)xab;
#pragma unroll
  for (int kk = 0; kk < 4; ++kk){
    sh8 aF = *(const sh8*)(xb + arow*CC + kk*32 + g*8);
    sh8 bF = *(const sh8*)(wqb + bcol*CC + kk*32 + g*8);
    acc = mfma32(aF, bF, acc);
  }
  int j = bcol;
  float bj = bias[j];
  int tbase = rt*16;
  int b  = tbase >> 12;
  int q0 = (tbase & 4095) + g*4;     // 4 consecutive within-batch slots
  if (j < CC){
    int h = j >> 5, d = j & 31;
    uint16_t* p = Qg + ((b*HH + h)*KTOK + q0)*DH + d;
#pragma unroll
    for (int i = 0; i < 4; ++i) p[i*DH] = f2bf((acc[i] + bj) * K2C);
  } else if (j < 2*CC){
    int jj = j - CC; int h = jj >> 5, d = jj & 31;
    uint16_t* p = Kg + ((b*HH + h)*KTOK + q0)*DH + d;
#pragma unroll
    for (int i = 0; i < 4; ++i) p[i*DH] = f2bf(acc[i] + bj);
  } else {
    int jj = j - 2*CC; int h = jj >> 5, d = jj & 31;
    uint16_t* p = Vt + ((b*HH + h)*DH + d)*KTOK + q0;
    ux2 w; w.x = pk2(acc[0]+bj, acc[1]+bj); w.y = pk2(acc[2]+bj, acc[3]+bj);
    *(ux2*)p = w;
  }
}

/* ---- K6: attention — block-shared staging, 2 q-tiles per block --------- */
/* 8 waves (512 thr): waves 0-3 = q-tile A, waves 4-7 = q-tile B; wave w
   computes key segment w&3 (1024 keys). K/V tiles are staged ONCE per
   block into shared LDS (wave w<4 stages K for seg w, w>=4 stages V for
   seg w-4; 2 gloads/wave/iter) -> staging L2 traffic + LDS writes HALVE
   vs R13. Sync = R7-proven: issue stage(t+1) -> compute(t) -> vmcnt(0) ->
   __syncthreads. Per-wave math byte-identical to R13 (32x32 swapped-QK,
   conflict-free swizzle, no-max softmax, cvt_pk + permlane32_swap).
   Combine: 4 segments x 2 tiles; waves 0 and 4 normalize + store. */
__global__ __launch_bounds__(512, 4) void k_attn(const uint16_t* __restrict__ Qg,
                                                 const uint16_t* __restrict__ Kg,
                                                 const uint16_t* __restrict__ Vtg,
                                                 uint16_t* __restrict__ O){
  __shared__ __align__(16) char lds[34944];
  int tid = threadIdx.x;
  int wv = tid >> 6, lane = tid & 63;
  int l31 = lane & 31, hi = lane >> 5;
  int seg = wv & 3, tq = wv >> 2;
  int bh = blockIdx.y;
  int qt = blockIdx.x;                 /* 64 q64-tiles per bh */
  const uint16_t* Qp = Qg  + bh*KTOK*DH;
  const uint16_t* Kp = Kg  + bh*KTOK*DH;
  const uint16_t* Vp = Vtg + bh*DH*KTOK;
  int q = qt*64 + tq*32 + l31;
  sh8 qF0 = *(const sh8*)(Qp + q*DH + hi*8);        /* B: col=q, k=dh 0..15  */
  sh8 qF1 = *(const sh8*)(Qp + q*DH + 16 + hi*8);   /* B: col=q, k=dh 16..31 */

  uint16_t* st = (uint16_t*)lds;   /* [2 buf][4 seg][K 1024 | V 1024] = 32KB */
  int key0 = seg*1024;
  int r16 = lane >> 2;
  int sx  = ((lane & 3) ^ ((r16 >> 1) & 3)) * 8;   /* pre-swizzled source slot */

  /* prologue: stage tile 0 -> buf0 (each wave stages its half of its seg) */
  if (wv < 4){
    const uint16_t* kg = Kp + key0*DH;
    uint16_t* d = st + seg*2048;
    gload_lds(kg + r16*DH + sx,      d + 0);
    gload_lds(kg + (16+r16)*DH + sx, d + 512);
  } else {
    const uint16_t* vg = Vp + key0;
    uint16_t* d = st + seg*2048 + 1024;
    gload_lds(vg + r16*KTOK + sx,      d + 0);
    gload_lds(vg + (16+r16)*KTOK + sx, d + 512);
  }
  asm volatile("s_waitcnt vmcnt(0)" ::: "memory");
  __syncthreads();

  fx16 acc = {0,0,0,0,0,0,0,0,0,0,0,0,0,0,0,0};
  const fx16 z16 = {0,0,0,0,0,0,0,0,0,0,0,0,0,0,0,0};
  float lsum = 0.f;
  int swz = (l31 >> 1) & 3;
  int koff0 = l31*32 + ((hi     ^ swz)*8);
  int koff1 = l31*32 + (((hi+2) ^ swz)*8);

  for (int t = 0; t < 32; ++t){
    int b = t & 1;
    if (t < 31){
      if (wv < 4){
        const uint16_t* kg = Kp + (key0 + (t+1)*32)*DH;
        uint16_t* d = st + ((b^1)*4 + seg)*2048;
        gload_lds(kg + r16*DH + sx,      d + 0);
        gload_lds(kg + (16+r16)*DH + sx, d + 512);
      } else {
        const uint16_t* vg = Vp + key0 + (t+1)*32;
        uint16_t* d = st + ((b^1)*4 + seg)*2048 + 1024;
        gload_lds(vg + r16*KTOK + sx,      d + 0);
        gload_lds(vg + (16+r16)*KTOK + sx, d + 512);
      }
    }
    const uint16_t* bK = st + (b*4 + seg)*2048;
    const uint16_t* bV = bK + 1024;
    sh8 kA0 = *(const sh8*)(bK + koff0);
    sh8 kA1 = *(const sh8*)(bK + koff1);
    fx16 S = mfma32x32(kA0, qF0, z16);
    S = mfma32x32(kA1, qF1, S);
    /* lane holds S for q, keys crow(r,hi)=(r&3)+8*(r>>2)+4*hi */
    float e[16];
#pragma unroll
    for (int r = 0; r < 16; ++r) e[r] = fast_exp2(S[r]);
    float ls = 0.f;
#pragma unroll
    for (int r = 0; r < 16; ++r) ls += e[r];
    lsum += ls;
    uint32_t X0 = cvtpk1(e[0], e[1]),   X1 = cvtpk1(e[2], e[3]);
    uint32_t X2 = cvtpk1(e[4], e[5]),   X3 = cvtpk1(e[6], e[7]);
    uint32_t X4 = cvtpk1(e[8], e[9]),   X5 = cvtpk1(e[10], e[11]);
    uint32_t X6 = cvtpk1(e[12], e[13]), X7 = cvtpk1(e[14], e[15]);
    plswap(X0, X2); plswap(X1, X3);
    plswap(X4, X6); plswap(X5, X7);
    ux4 w0, w1;
    w0.x = X0; w0.y = X1; w0.z = X2; w0.w = X3;
    w1.x = X4; w1.y = X5; w1.z = X6; w1.w = X7;
    sh8 pa0 = *(sh8*)&w0;   /* A: row=q, k=keys 0..15 of tile  */
    sh8 pa1 = *(sh8*)&w1;   /* A: row=q, k=keys 16..31 of tile */
    sh8 vB0 = *(const sh8*)(bV + koff0);   /* B: col=dh, k=keys 0..15  */
    sh8 vB1 = *(const sh8*)(bV + koff1);   /* B: col=dh, k=keys 16..31 */
    acc = mfma32x32(pa0, vB0, acc);
    acc = mfma32x32(pa1, vB1, acc);
    asm volatile("s_waitcnt vmcnt(0)" ::: "memory");
    __syncthreads();
  }

  /* combine 4 segments x 2 tiles; staging LDS reused (all past final barrier) */
  float* cmb = (float*)lds;                    /* [2 tq][4 seg][64][16] = 32KB */
  float* lwp = (float*)(lds + 32768);          /* [8][32]                      */
  float* ltr = (float*)(lds + 32768 + 1024);   /* [2][32]                      */
  lsum += __shfl_xor(lsum, 32);                /* seg-total l for this q       */
#pragma unroll
  for (int i = 0; i < 16; i += 4){
    fx4 p = {acc[i], acc[i+1], acc[i+2], acc[i+3]};
    *(fx4*)&cmb[((tq*4 + seg)*64 + lane)*16 + i] = p;
  }
  if (!hi) lwp[wv*32 + l31] = lsum;
  __syncthreads();
  if (seg == 0){   /* waves 0 (tile A) and 4 (tile B) */
#pragma unroll
    for (int s = 1; s < 4; ++s){
#pragma unroll
      for (int i = 0; i < 16; i += 4){
        fx4 p = *(const fx4*)&cmb[((tq*4 + s)*64 + lane)*16 + i];
        acc[i] += p.x; acc[i+1] += p.y; acc[i+2] += p.z; acc[i+3] += p.w;
      }
    }
    float lt = (lwp[(tq*4+0)*32 + l31] + lwp[(tq*4+1)*32 + l31])
             + (lwp[(tq*4+2)*32 + l31] + lwp[(tq*4+3)*32 + l31]);
    if (!hi) ltr[tq*32 + l31] = lt;
    fx4 La = *(const fx4*)&ltr[tq*32 + 4*hi];
    fx4 Lb = *(const fx4*)&ltr[tq*32 + 8 + 4*hi];
    fx4 Lc = *(const fx4*)&ltr[tq*32 + 16 + 4*hi];
    fx4 Ld = *(const fx4*)&ltr[tq*32 + 24 + 4*hi];
    fx4 Ra = {1.f/La.x, 1.f/La.y, 1.f/La.z, 1.f/La.w};
    fx4 Rb = {1.f/Lb.x, 1.f/Lb.y, 1.f/Lb.z, 1.f/Lb.w};
    fx4 Rc = {1.f/Lc.x, 1.f/Lc.y, 1.f/Lc.z, 1.f/Lc.w};
    fx4 Rd = {1.f/Ld.x, 1.f/Ld.y, 1.f/Ld.z, 1.f/Ld.w};
    int bb = bh >> 2, h = bh & 3;
    uint16_t* op = O + (bb*KTOK + qt*64 + tq*32)*CC + h*DH + l31;
#pragma unroll
    for (int r = 0; r < 16; ++r){
      int qd = (r&3) + 8*(r>>2) + 4*hi;
      float rv = (r<4) ? Ra[r&3] : (r<8) ? Rb[r&3] : (r<12) ? Rc[r&3] : Rd[r&3];
      op[qd*CC] = f2bf(acc[r] * rv);
    }
  }
}

/* ---------------- K7: out-proj + residual + LayerNorm + scatter --------- */
__global__ __launch_bounds__(256) void k_outln(const uint16_t* __restrict__ O,
                                               const uint16_t* __restrict__ wob,
                                               const float* __restrict__ bo,
                                               const float* __restrict__ feats,
                                               const int* __restrict__ sel,
                                               const float* __restrict__ lnw,
                                               const float* __restrict__ lnb,
                                               float* __restrict__ out){
  __shared__ float red[16][4][2];
  int wave = threadIdx.x >> 6, lane = threadIdx.x & 63;
  int l15 = lane & 15, g = lane >> 4;
  int rt = blockIdx.x;
  int arow = rt*16 + l15;
  int jA = wave*32 + l15, jB = jA + 16;
  fx4 accA = {0,0,0,0}, accB = {0,0,0,0};
#pragma unroll
  for (int kk = 0; kk < 4; ++kk){
    sh8 aF = *(const sh8*)(O   + arow*CC + kk*32 + g*8);
    sh8 b0 = *(const sh8*)(wob + jA*CC   + kk*32 + g*8);
    sh8 b1 = *(const sh8*)(wob + jB*CC   + kk*32 + g*8);
    accA = mfma32(aF, b0, accA);
    accB = mfma32(aF, b1, accB);
  }
  float bjA = bo[jA], bjB = bo[jB];
  float hA[4], hB[4]; int gl[4];
#pragma unroll
  for (int i = 0; i < 4; ++i){
    int r = rt*16 + g*4 + i;
    int grow = sel[r];
    gl[i] = grow;
    hA[i] = accA[i] + bjA + feats[grow*CC + jA];
    hB[i] = accB[i] + bjB + feats[grow*CC + jB];
  }
#pragma unroll
  for (int i = 0; i < 4; ++i){
    float s  = hA[i] + hB[i];
    float s2 = hA[i]*hA[i] + hB[i]*hB[i];
    for (int mk = 1; mk < 16; mk <<= 1){ s += __shfl_xor(s, mk); s2 += __shfl_xor(s2, mk); }
    if (l15 == 0){ red[g*4+i][wave][0] = s; red[g*4+i][wave][1] = s2; }
  }
  __syncthreads();
  float w0 = lnw[jA], w1 = lnw[jB], b0v = lnb[jA], b1v = lnb[jB];
#pragma unroll
  for (int i = 0; i < 4; ++i){
    int rl = g*4 + i;
    float tot  = red[rl][0][0] + red[rl][1][0] + red[rl][2][0] + red[rl][3][0];
    float tot2 = red[rl][0][1] + red[rl][1][1] + red[rl][2][1] + red[rl][3][1];
    float mu  = tot  * (1.f/128.f);
    float var = tot2 * (1.f/128.f) - mu*mu;
    float rs = rsqrtf(var + 1e-5f);
    out[gl[i]*CC + jA] = (hA[i]-mu)*rs*w0 + b0v;
    out[gl[i]*CC + jB] = (hB[i]-mu)*rs*w1 + b1v;
  }
}

extern "C" void kernel_launch(void* const* d_in, const int* in_sizes, int n_in,
                              void* d_out, int out_size, void* d_ws, size_t ws_size,
                              hipStream_t stream){
  const float* feats = (const float*)d_in[0];
  /* d_in[1] = batch_idx (int64) — contiguous equal groups, unused */
  const float* wqkv  = (const float*)d_in[2];
  const float* bqkv  = (const float*)d_in[3];
  const float* wout  = (const float*)d_in[4];
  const float* bout  = (const float*)d_in[5];
  const float* lnw   = (const float*)d_in[6];
  const float* lnb   = (const float*)d_in[7];
  float* out = (float*)d_out;
  char* ws = (char*)d_ws;

  uint32_t* keys = (uint32_t*)(ws + 0);        /* 64KB  */
  int*      sel  = (int*)     (ws + 65536);    /* 32KB  */
  uint16_t* wqb  = (uint16_t*)(ws + 98304);    /* 96KB  */
  uint16_t* wob  = (uint16_t*)(ws + 196608);   /* 32KB  */
  uint32_t* xab  = (uint32_t*)(ws + 229376);   /* 2MB   */
  uint16_t* Qg   = (uint16_t*)(ws + 2326528);  /* 2MB   */
  uint16_t* Kg   = (uint16_t*)(ws + 4423680);  /* 2MB   */
  uint16_t* Vt   = (uint16_t*)(ws + 6520832);  /* 2MB   */
  uint16_t* O    = (uint16_t*)(ws + 8617984);  /* 2MB   */

  hipLaunchKernelGGL(k_cpnw,   dim3(1280),   dim3(256),  0, stream,
                     feats, out, keys, wqkv, wout, wqb, wob);
  hipLaunchKernelGGL(k_select, dim3(2),      dim3(1024), 0, stream, keys, sel);
  hipLaunchKernelGGL(k_gather, dim3(2048),   dim3(256),  0, stream, feats, sel, xab);
  hipLaunchKernelGGL(k_qkv,    dim3(512,6),  dim3(256),  0, stream, xab, wqb, bqkv, Qg, Kg, Vt);
  hipLaunchKernelGGL(k_attn,   dim3(64,8),   dim3(512),  0, stream, Qg, Kg, Vt, O);
  hipLaunchKernelGGL(k_outln,  dim3(512),    dim3(256),  0, stream, O, wob, bout, feats, sel, lnw, lnb, out);
}

// Round 15
// 80.686 us; speedup vs baseline: 1.2510x; 1.0544x over previous
//
#include <hip/hip_runtime.h>
#include <hip/hip_bf16.h>
#include <stdint.h>

#define NPB 8192
#define CB 2
#define CC 128
#define HH 4
#define KTOK 4096
#define DH 32
#define NTOK (CB*KTOK)
#define K2C 0.25503402f  /* log2(e)/sqrt(32) */

typedef __attribute__((ext_vector_type(8))) short sh8;
typedef __attribute__((ext_vector_type(4))) float fx4;
typedef __attribute__((ext_vector_type(16))) float fx16;
typedef __attribute__((ext_vector_type(2))) uint32_t ux2;
typedef __attribute__((ext_vector_type(4))) uint32_t ux4;

__device__ inline uint16_t f2bf(float f){
  uint32_t x = __float_as_uint(f);
  return (uint16_t)((x + 0x7FFFu + ((x>>16)&1u)) >> 16);
}
__device__ inline uint32_t pk2(float a, float b){
  return (uint32_t)f2bf(a) | ((uint32_t)f2bf(b) << 16);
}
__device__ inline float fast_exp2(float x){
#if __has_builtin(__builtin_amdgcn_exp2f)
  return __builtin_amdgcn_exp2f(x);
#else
  return exp2f(x);
#endif
}
__device__ inline uint32_t cvtpk1(float a, float b){
  uint32_t u;
  asm("v_cvt_pk_bf16_f32 %0, %1, %2" : "=v"(u) : "v"(a), "v"(b));
  return u;
}
/* exchange halves across lane<32/lane>=32 (R13-proven) */
__device__ inline void plswap(uint32_t& a, uint32_t& b){
#if __has_builtin(__builtin_amdgcn_permlane32_swap)
  typedef __attribute__((ext_vector_type(2))) unsigned int u2;
  u2 r = __builtin_amdgcn_permlane32_swap(a, b, false, false);
  a = r.x; b = r.y;
#else
  int hi = (threadIdx.x & 63) >> 5;
  uint32_t t = __shfl_xor(hi ? a : b, 32);
  uint32_t na = hi ? t : a;
  uint32_t nb = hi ? b : t;
  a = na; b = nb;
#endif
}
__device__ inline fx4 mfma32(sh8 a, sh8 b, fx4 c){
  return __builtin_amdgcn_mfma_f32_16x16x32_bf16(a, b, c, 0, 0, 0);
}
__device__ inline fx16 mfma32x32(sh8 a, sh8 b, fx16 c){
  return __builtin_amdgcn_mfma_f32_32x32x16_bf16(a, b, c, 0, 0, 0);
}
__device__ inline void gload_lds(const uint16_t* g, uint16_t* l){
  __builtin_amdgcn_global_load_lds(
      (const __attribute__((address_space(1))) uint32_t*)g,
      (__attribute__((address_space(3))) uint32_t*)l,
      16, 0, 0);
}

/* -------- K0: copy feats -> out + sqnorm keys + weight conversion ------- */
__global__ __launch_bounds__(256) void k_cpnw(const float* __restrict__ feats,
                                              float* __restrict__ out,
                                              uint32_t* __restrict__ keys,
                                              const float* __restrict__ wq,
                                              const float* __restrict__ wo,
                                              uint16_t* __restrict__ wqb,
                                              uint16_t* __restrict__ wob){
  int bx = blockIdx.x;
  if (bx < 1024){
    int wv = threadIdx.x >> 6, lane = threadIdx.x & 63;
    int row0 = bx*16 + wv*4;
#pragma unroll
    for (int r = 0; r < 4; ++r){
      int row = row0 + r;
      float2 v = *(const float2*)(feats + row*CC + lane*2);
      *(float2*)(out + row*CC + lane*2) = v;
      float s = v.x*v.x + v.y*v.y;
      for (int m = 1; m < 64; m <<= 1) s += __shfl_xor(s, m);
      if (lane == 0) keys[row] = __float_as_uint(s);
    }
  } else {
    int i = (bx - 1024)*256 + threadIdx.x;   /* 0..65535 */
    if (i < 3*CC*CC) wqb[i] = f2bf(wq[i]);
    else { int j = i - 3*CC*CC; wob[j] = f2bf(wo[j]); }
  }
}

/* ---------------- K2: exact top-4096 selection per batch ---------------- */
__global__ __launch_bounds__(1024) void k_select(const uint32_t* __restrict__ keys,
                                                 int* __restrict__ sel){
  __shared__ uint32_t ka[NPB];
  __shared__ uint32_t hist[16*257];
  __shared__ uint32_t comb[256];
  __shared__ uint32_t sh_prefix, sh_r;
  __shared__ int wsum[17];
  int tid = threadIdx.x, batch = blockIdx.x;
  int wv16 = tid >> 6;
  for (int i = tid; i < NPB; i += 1024) ka[i] = keys[batch*NPB + i];
  if (tid == 0){ sh_prefix = 0u; sh_r = KTOK; }
  __syncthreads();
  for (int pass = 0; pass < 4; ++pass){
    int shift = 24 - 8*pass;
    for (int i = tid; i < 16*257; i += 1024) hist[i] = 0u;
    __syncthreads();
    uint32_t pref = sh_prefix;
    uint32_t r0   = sh_r;
    uint32_t mask = (pass == 0) ? 0u : (0xFFFFFFFFu << (shift + 8));
    uint32_t* myh = &hist[wv16*257];
    for (int e = 0; e < 8; ++e){
      uint32_t k = ka[tid*8 + e];
      if ((k & mask) == pref) atomicAdd(&myh[(k >> shift) & 255], 1u);
    }
    __syncthreads();
    uint32_t h0 = 0;
    if (tid < 256){
      for (int w = 0; w < 16; ++w) h0 += hist[w*257 + tid];
      comb[tid] = h0;
    }
    __syncthreads();
    for (int off = 1; off < 256; off <<= 1){
      uint32_t v = (tid < 256 && tid + off < 256) ? comb[tid + off] : 0u;
      __syncthreads();
      if (tid < 256) comb[tid] += v;
      __syncthreads();
    }
    if (tid < 256){
      uint32_t incl = comb[tid];
      uint32_t Sx   = incl - h0;
      if (Sx < r0 && incl >= r0){
        sh_prefix = pref | ((uint32_t)tid << shift);
        sh_r = r0 - Sx;
      }
    }
    __syncthreads();
  }
  uint32_t T = sh_prefix; int need = (int)sh_r;
  int lgt = 0, leq = 0;
  for (int e = 0; e < 8; ++e){
    uint32_t k = ka[tid*8 + e];
    lgt += (k > T); leq += (k == T);
  }
  int lane = tid & 63, wv = tid >> 6;
  int egt, tgt, eeq;
  {
    __syncthreads();
    int incl = lgt;
    for (int d = 1; d < 64; d <<= 1){ int t = __shfl_up(incl, d); if (lane >= d) incl += t; }
    if (lane == 63) wsum[wv] = incl;
    __syncthreads();
    if (tid == 0){ int run = 0; for (int w = 0; w < 16; ++w){ int t = wsum[w]; wsum[w] = run; run += t; } wsum[16] = run; }
    __syncthreads();
    egt = wsum[wv] + incl - lgt; tgt = wsum[16];
  }
  {
    __syncthreads();
    int incl = leq;
    for (int d = 1; d < 64; d <<= 1){ int t = __shfl_up(incl, d); if (lane >= d) incl += t; }
    if (lane == 63) wsum[wv] = incl;
    __syncthreads();
    if (tid == 0){ int run = 0; for (int w = 0; w < 16; ++w){ int t = wsum[w]; wsum[w] = run; run += t; } }
    __syncthreads();
    eeq = wsum[wv] + incl - leq;
  }
  int chi = tgt, gpos = egt, epos = eeq;
  for (int e = 0; e < 8; ++e){
    int i = tid*8 + e;
    uint32_t k = ka[i];
    if (k > T){ sel[batch*KTOK + (gpos++)] = batch*NPB + i; }
    else if (k == T){ if (epos < need) sel[batch*KTOK + chi + epos] = batch*NPB + i; epos++; }
  }
}

/* ---------------- K4: gather selected rows to bf16 ---------------------- */
__global__ __launch_bounds__(256) void k_gather(const float* __restrict__ feats,
                                                const int* __restrict__ sel,
                                                uint32_t* __restrict__ xab){
  int t    = blockIdx.x*4 + (threadIdx.x>>6);
  int lane = threadIdx.x & 63;
  int g = sel[t];
  float2 v = *(const float2*)(feats + g*CC + lane*2);
  xab[t*(CC/2) + lane] = pk2(v.x, v.y);
}

/* ---------------- K5: QKV projection GEMM (8192x384x128) ---------------- */
/* Q is pre-scaled by log2(e)/sqrt(Dh) so attention uses exp2 directly.    */
__global__ __launch_bounds__(256) void k_qkv(const uint32_t* __restrict__ xab,
                                             const uint16_t* __restrict__ wqb,
                                             const float* __restrict__ bias,
                                             uint16_t* __restrict__ Qg,
                                             uint16_t* __restrict__ Kg,
                                             uint16_t* __restrict__ Vt){
  int wave = threadIdx.x >> 6, lane = threadIdx.x & 63;
  int l15 = lane & 15, g = lane >> 4;
  int rt = blockIdx.x;               // 512 row tiles
  int ct = blockIdx.y*4 + wave;      // 24 col tiles
  int arow = rt*16 + l15;
  int bcol = ct*16 + l15;
  fx4 acc = {0.f,0.f,0.f,0.f};
  const uint16_t* xb = (const uint16_t*)xab;
#pragma unroll
  for (int kk = 0; kk < 4; ++kk){
    sh8 aF = *(const sh8*)(xb + arow*CC + kk*32 + g*8);
    sh8 bF = *(const sh8*)(wqb + bcol*CC + kk*32 + g*8);
    acc = mfma32(aF, bF, acc);
  }
  int j = bcol;
  float bj = bias[j];
  int tbase = rt*16;
  int b  = tbase >> 12;
  int q0 = (tbase & 4095) + g*4;     // 4 consecutive within-batch slots
  if (j < CC){
    int h = j >> 5, d = j & 31;
    uint16_t* p = Qg + ((b*HH + h)*KTOK + q0)*DH + d;
#pragma unroll
    for (int i = 0; i < 4; ++i) p[i*DH] = f2bf((acc[i] + bj) * K2C);
  } else if (j < 2*CC){
    int jj = j - CC; int h = jj >> 5, d = jj & 31;
    uint16_t* p = Kg + ((b*HH + h)*KTOK + q0)*DH + d;
#pragma unroll
    for (int i = 0; i < 4; ++i) p[i*DH] = f2bf(acc[i] + bj);
  } else {
    int jj = j - 2*CC; int h = jj >> 5, d = jj & 31;
    uint16_t* p = Vt + ((b*HH + h)*DH + d)*KTOK + q0;
    ux2 w; w.x = pk2(acc[0]+bj, acc[1]+bj); w.y = pk2(acc[2]+bj, acc[3]+bj);
    *(ux2*)p = w;
  }
}

/* ---- K6: attention — block-shared staging, TK=64 (2 sub-tiles/buffer) -- */
/* R14 structure (8 waves, 2 q-tiles x 4 segments, block-shared staging,
   proven sync: issue stage(t+1) -> compute(t) -> vmcnt(0) -> syncthreads)
   with the staged chunk doubled to 64 keys = two R14-layout 32-key
   sub-tiles [K0|K1|V0|V1]. Per-drain compute doubles (~300cyc) so the
   staged-load latency is mostly covered; barrier count halves (32->16).
   Per-sub-tile math/swizzle/permlane byte-identical to R14.
   LDS = 2 buf x 4 seg x 8KB = 64KB (2 blocks/CU, grid-limited anyway). */
__global__ __launch_bounds__(512, 4) void k_attn(const uint16_t* __restrict__ Qg,
                                                 const uint16_t* __restrict__ Kg,
                                                 const uint16_t* __restrict__ Vtg,
                                                 uint16_t* __restrict__ O){
  __shared__ __align__(16) char lds[65536];
  int tid = threadIdx.x;
  int wv = tid >> 6, lane = tid & 63;
  int l31 = lane & 31, hi = lane >> 5;
  int seg = wv & 3, tq = wv >> 2;
  int bh = blockIdx.y;
  int qt = blockIdx.x;                 /* 64 q64-tiles per bh */
  const uint16_t* Qp = Qg  + bh*KTOK*DH;
  const uint16_t* Kp = Kg  + bh*KTOK*DH;
  const uint16_t* Vp = Vtg + bh*DH*KTOK;
  int q = qt*64 + tq*32 + l31;
  sh8 qF0 = *(const sh8*)(Qp + q*DH + hi*8);        /* B: col=q, k=dh 0..15  */
  sh8 qF1 = *(const sh8*)(Qp + q*DH + 16 + hi*8);   /* B: col=q, k=dh 16..31 */

  uint16_t* st = (uint16_t*)lds;   /* [2 buf][4 seg][K0|K1|V0|V1] 1024-elem blocks */
  int key0 = seg*1024;
  int r16 = lane >> 2;
  int sx  = ((lane & 3) ^ ((r16 >> 1) & 3)) * 8;   /* pre-swizzled source slot */

  /* stage one 64-key chunk for this seg: wave<4 stages K (4 gloads),
     wave>=4 stages V (4 gloads); dest blocks of 1024 elems             */
  /* prologue: chunk 0 -> buf0 */
  {
    if (wv < 4){
      const uint16_t* kg = Kp + key0*DH;
      uint16_t* d = st + seg*4096;
#pragma unroll
      for (int ks = 0; ks < 2; ++ks){
        gload_lds(kg + (ks*32 + r16)*DH + sx,      d + ks*1024 + 0);
        gload_lds(kg + (ks*32 + 16 + r16)*DH + sx, d + ks*1024 + 512);
      }
    } else {
      const uint16_t* vg = Vp + key0;
      uint16_t* d = st + seg*4096 + 2048;
#pragma unroll
      for (int ks = 0; ks < 2; ++ks){
        gload_lds(vg + r16*KTOK + ks*32 + sx,        d + ks*1024 + 0);
        gload_lds(vg + (16+r16)*KTOK + ks*32 + sx,   d + ks*1024 + 512);
      }
    }
  }
  asm volatile("s_waitcnt vmcnt(0)" ::: "memory");
  __syncthreads();

  fx16 acc = {0,0,0,0,0,0,0,0,0,0,0,0,0,0,0,0};
  const fx16 z16 = {0,0,0,0,0,0,0,0,0,0,0,0,0,0,0,0};
  float lsum = 0.f;
  int swz = (l31 >> 1) & 3;
  int koff0 = l31*32 + ((hi     ^ swz)*8);
  int koff1 = l31*32 + (((hi+2) ^ swz)*8);

  for (int t = 0; t < 16; ++t){
    int b = t & 1;
    if (t < 15){
      int nk = key0 + (t+1)*64;
      if (wv < 4){
        const uint16_t* kg = Kp + nk*DH;
        uint16_t* d = st + ((b^1)*4 + seg)*4096;
#pragma unroll
        for (int ks = 0; ks < 2; ++ks){
          gload_lds(kg + (ks*32 + r16)*DH + sx,      d + ks*1024 + 0);
          gload_lds(kg + (ks*32 + 16 + r16)*DH + sx, d + ks*1024 + 512);
        }
      } else {
        const uint16_t* vg = Vp + nk;
        uint16_t* d = st + ((b^1)*4 + seg)*4096 + 2048;
#pragma unroll
        for (int ks = 0; ks < 2; ++ks){
          gload_lds(vg + r16*KTOK + ks*32 + sx,        d + ks*1024 + 0);
          gload_lds(vg + (16+r16)*KTOK + ks*32 + sx,   d + ks*1024 + 512);
        }
      }
    }
    const uint16_t* base = st + (b*4 + seg)*4096;
#pragma unroll
    for (int ks = 0; ks < 2; ++ks){
      const uint16_t* bK = base + ks*1024;
      const uint16_t* bV = base + 2048 + ks*1024;
      sh8 kA0 = *(const sh8*)(bK + koff0);
      sh8 kA1 = *(const sh8*)(bK + koff1);
      fx16 S = mfma32x32(kA0, qF0, z16);
      S = mfma32x32(kA1, qF1, S);
      /* lane holds S for q, keys crow(r,hi)=(r&3)+8*(r>>2)+4*hi */
      float e[16];
#pragma unroll
      for (int r = 0; r < 16; ++r) e[r] = fast_exp2(S[r]);
      float ls = 0.f;
#pragma unroll
      for (int r = 0; r < 16; ++r) ls += e[r];
      lsum += ls;
      uint32_t X0 = cvtpk1(e[0], e[1]),   X1 = cvtpk1(e[2], e[3]);
      uint32_t X2 = cvtpk1(e[4], e[5]),   X3 = cvtpk1(e[6], e[7]);
      uint32_t X4 = cvtpk1(e[8], e[9]),   X5 = cvtpk1(e[10], e[11]);
      uint32_t X6 = cvtpk1(e[12], e[13]), X7 = cvtpk1(e[14], e[15]);
      plswap(X0, X2); plswap(X1, X3);
      plswap(X4, X6); plswap(X5, X7);
      ux4 w0, w1;
      w0.x = X0; w0.y = X1; w0.z = X2; w0.w = X3;
      w1.x = X4; w1.y = X5; w1.z = X6; w1.w = X7;
      sh8 pa0 = *(sh8*)&w0;   /* A: row=q, k=keys 0..15 of sub-tile  */
      sh8 pa1 = *(sh8*)&w1;   /* A: row=q, k=keys 16..31 of sub-tile */
      sh8 vB0 = *(const sh8*)(bV + koff0);   /* B: col=dh, k=keys 0..15  */
      sh8 vB1 = *(const sh8*)(bV + koff1);   /* B: col=dh, k=keys 16..31 */
      acc = mfma32x32(pa0, vB0, acc);
      acc = mfma32x32(pa1, vB1, acc);
    }
    asm volatile("s_waitcnt vmcnt(0)" ::: "memory");
    __syncthreads();
  }

  /* combine 4 segments x 2 tiles; staging LDS reused (all past final barrier) */
  float* cmb = (float*)lds;                    /* [2 tq][4 seg][64][16] = 32KB */
  float* lwp = (float*)(lds + 32768);          /* [8][32]                      */
  float* ltr = (float*)(lds + 32768 + 1024);   /* [2][32]                      */
  lsum += __shfl_xor(lsum, 32);                /* seg-total l for this q       */
#pragma unroll
  for (int i = 0; i < 16; i += 4){
    fx4 p = {acc[i], acc[i+1], acc[i+2], acc[i+3]};
    *(fx4*)&cmb[((tq*4 + seg)*64 + lane)*16 + i] = p;
  }
  if (!hi) lwp[wv*32 + l31] = lsum;
  __syncthreads();
  if (seg == 0){   /* waves 0 (tile A) and 4 (tile B) */
#pragma unroll
    for (int s = 1; s < 4; ++s){
#pragma unroll
      for (int i = 0; i < 16; i += 4){
        fx4 p = *(const fx4*)&cmb[((tq*4 + s)*64 + lane)*16 + i];
        acc[i] += p.x; acc[i+1] += p.y; acc[i+2] += p.z; acc[i+3] += p.w;
      }
    }
    float lt = (lwp[(tq*4+0)*32 + l31] + lwp[(tq*4+1)*32 + l31])
             + (lwp[(tq*4+2)*32 + l31] + lwp[(tq*4+3)*32 + l31]);
    if (!hi) ltr[tq*32 + l31] = lt;
    fx4 La = *(const fx4*)&ltr[tq*32 + 4*hi];
    fx4 Lb = *(const fx4*)&ltr[tq*32 + 8 + 4*hi];
    fx4 Lc = *(const fx4*)&ltr[tq*32 + 16 + 4*hi];
    fx4 Ld = *(const fx4*)&ltr[tq*32 + 24 + 4*hi];
    fx4 Ra = {1.f/La.x, 1.f/La.y, 1.f/La.z, 1.f/La.w};
    fx4 Rb = {1.f/Lb.x, 1.f/Lb.y, 1.f/Lb.z, 1.f/Lb.w};
    fx4 Rc = {1.f/Lc.x, 1.f/Lc.y, 1.f/Lc.z, 1.f/Lc.w};
    fx4 Rd = {1.f/Ld.x, 1.f/Ld.y, 1.f/Ld.z, 1.f/Ld.w};
    int bb = bh >> 2, h = bh & 3;
    uint16_t* op = O + (bb*KTOK + qt*64 + tq*32)*CC + h*DH + l31;
#pragma unroll
    for (int r = 0; r < 16; ++r){
      int qd = (r&3) + 8*(r>>2) + 4*hi;
      float rv = (r<4) ? Ra[r&3] : (r<8) ? Rb[r&3] : (r<12) ? Rc[r&3] : Rd[r&3];
      op[qd*CC] = f2bf(acc[r] * rv);
    }
  }
}

/* ---------------- K7: out-proj + residual + LayerNorm + scatter --------- */
__global__ __launch_bounds__(256) void k_outln(const uint16_t* __restrict__ O,
                                               const uint16_t* __restrict__ wob,
                                               const float* __restrict__ bo,
                                               const float* __restrict__ feats,
                                               const int* __restrict__ sel,
                                               const float* __restrict__ lnw,
                                               const float* __restrict__ lnb,
                                               float* __restrict__ out){
  __shared__ float red[16][4][2];
  int wave = threadIdx.x >> 6, lane = threadIdx.x & 63;
  int l15 = lane & 15, g = lane >> 4;
  int rt = blockIdx.x;
  int arow = rt*16 + l15;
  int jA = wave*32 + l15, jB = jA + 16;
  fx4 accA = {0,0,0,0}, accB = {0,0,0,0};
#pragma unroll
  for (int kk = 0; kk < 4; ++kk){
    sh8 aF = *(const sh8*)(O   + arow*CC + kk*32 + g*8);
    sh8 b0 = *(const sh8*)(wob + jA*CC   + kk*32 + g*8);
    sh8 b1 = *(const sh8*)(wob + jB*CC   + kk*32 + g*8);
    accA = mfma32(aF, b0, accA);
    accB = mfma32(aF, b1, accB);
  }
  float bjA = bo[jA], bjB = bo[jB];
  float hA[4], hB[4]; int gl[4];
#pragma unroll
  for (int i = 0; i < 4; ++i){
    int r = rt*16 + g*4 + i;
    int grow = sel[r];
    gl[i] = grow;
    hA[i] = accA[i] + bjA + feats[grow*CC + jA];
    hB[i] = accB[i] + bjB + feats[grow*CC + jB];
  }
#pragma unroll
  for (int i = 0; i < 4; ++i){
    float s  = hA[i] + hB[i];
    float s2 = hA[i]*hA[i] + hB[i]*hB[i];
    for (int mk = 1; mk < 16; mk <<= 1){ s += __shfl_xor(s, mk); s2 += __shfl_xor(s2, mk); }
    if (l15 == 0){ red[g*4+i][wave][0] = s; red[g*4+i][wave][1] = s2; }
  }
  __syncthreads();
  float w0 = lnw[jA], w1 = lnw[jB], b0v = lnb[jA], b1v = lnb[jB];
#pragma unroll
  for (int i = 0; i < 4; ++i){
    int rl = g*4 + i;
    float tot  = red[rl][0][0] + red[rl][1][0] + red[rl][2][0] + red[rl][3][0];
    float tot2 = red[rl][0][1] + red[rl][1][1] + red[rl][2][1] + red[rl][3][1];
    float mu  = tot  * (1.f/128.f);
    float var = tot2 * (1.f/128.f) - mu*mu;
    float rs = rsqrtf(var + 1e-5f);
    out[gl[i]*CC + jA] = (hA[i]-mu)*rs*w0 + b0v;
    out[gl[i]*CC + jB] = (hB[i]-mu)*rs*w1 + b1v;
  }
}

extern "C" void kernel_launch(void* const* d_in, const int* in_sizes, int n_in,
                              void* d_out, int out_size, void* d_ws, size_t ws_size,
                              hipStream_t stream){
  const float* feats = (const float*)d_in[0];
  /* d_in[1] = batch_idx (int64) — contiguous equal groups, unused */
  const float* wqkv  = (const float*)d_in[2];
  const float* bqkv  = (const float*)d_in[3];
  const float* wout  = (const float*)d_in[4];
  const float* bout  = (const float*)d_in[5];
  const float* lnw   = (const float*)d_in[6];
  const float* lnb   = (const float*)d_in[7];
  float* out = (float*)d_out;
  char* ws = (char*)d_ws;

  uint32_t* keys = (uint32_t*)(ws + 0);        /* 64KB  */
  int*      sel  = (int*)     (ws + 65536);    /* 32KB  */
  uint16_t* wqb  = (uint16_t*)(ws + 98304);    /* 96KB  */
  uint16_t* wob  = (uint16_t*)(ws + 196608);   /* 32KB  */
  uint32_t* xab  = (uint32_t*)(ws + 229376);   /* 2MB   */
  uint16_t* Qg   = (uint16_t*)(ws + 2326528);  /* 2MB   */
  uint16_t* Kg   = (uint16_t*)(ws + 4423680);  /* 2MB   */
  uint16_t* Vt   = (uint16_t*)(ws + 6520832);  /* 2MB   */
  uint16_t* O    = (uint16_t*)(ws + 8617984);  /* 2MB   */

  hipLaunchKernelGGL(k_cpnw,   dim3(1280),   dim3(256),  0, stream,
                     feats, out, keys, wqkv, wout, wqb, wob);
  hipLaunchKernelGGL(k_select, dim3(2),      dim3(1024), 0, stream, keys, sel);
  hipLaunchKernelGGL(k_gather, dim3(2048),   dim3(256),  0, stream, feats, sel, xab);
  hipLaunchKernelGGL(k_qkv,    dim3(512,6),  dim3(256),  0, stream, xab, wqb, bqkv, Qg, Kg, Vt);
  hipLaunchKernelGGL(k_attn,   dim3(64,8),   dim3(512),  0, stream, Qg, Kg, Vt, O);
  hipLaunchKernelGGL(k_outln,  dim3(512),    dim3(256),  0, stream, O, wob, bout, feats, sel, lnw, lnb, out);
}

// Round 16
// 73.817 us; speedup vs baseline: 1.3674x; 1.0931x over previous
//
#include <hip/hip_runtime.h>
#include <hip/hip_bf16.h>
#include <stdint.h>

#define NPB 8192
#define CB 2
#define CC 128
#define HH 4
#define KTOK 4096
#define DH 32
#define NTOK (CB*KTOK)
#define K2C 0.25503402f  /* log2(e)/sqrt(32) */

typedef __attribute__((ext_vector_type(8))) short sh8;
typedef __attribute__((ext_vector_type(4))) float fx4;
typedef __attribute__((ext_vector_type(16))) float fx16;
typedef __attribute__((ext_vector_type(2))) uint32_t ux2;
typedef __attribute__((ext_vector_type(4))) uint32_t ux4;

__device__ inline uint16_t f2bf(float f){
  uint32_t x = __float_as_uint(f);
  return (uint16_t)((x + 0x7FFFu + ((x>>16)&1u)) >> 16);
}
__device__ inline uint32_t pk2(float a, float b){
  return (uint32_t)f2bf(a) | ((uint32_t)f2bf(b) << 16);
}
__device__ inline float fast_exp2(float x){
#if __has_builtin(__builtin_amdgcn_exp2f)
  return __builtin_amdgcn_exp2f(x);
#else
  return exp2f(x);
#endif
}
__device__ inline uint32_t cvtpk1(float a, float b){
  uint32_t u;
  asm("v_cvt_pk_bf16_f32 %0, %1, %2" : "=v"(u) : "v"(a), "v"(b));
  return u;
}
/* exchange halves across lane<32/lane>=32 (R13-proven) */
__device__ inline void plswap(uint32_t& a, uint32_t& b){
#if __has_builtin(__builtin_amdgcn_permlane32_swap)
  typedef __attribute__((ext_vector_type(2))) unsigned int u2;
  u2 r = __builtin_amdgcn_permlane32_swap(a, b, false, false);
  a = r.x; b = r.y;
#else
  int hi = (threadIdx.x & 63) >> 5;
  uint32_t t = __shfl_xor(hi ? a : b, 32);
  uint32_t na = hi ? t : a;
  uint32_t nb = hi ? b : t;
  a = na; b = nb;
#endif
}
__device__ inline fx4 mfma32(sh8 a, sh8 b, fx4 c){
  return __builtin_amdgcn_mfma_f32_16x16x32_bf16(a, b, c, 0, 0, 0);
}
__device__ inline fx16 mfma32x32(sh8 a, sh8 b, fx16 c){
  return __builtin_amdgcn_mfma_f32_32x32x16_bf16(a, b, c, 0, 0, 0);
}
__device__ inline void gload_lds(const uint16_t* g, uint16_t* l){
  __builtin_amdgcn_global_load_lds(
      (const __attribute__((address_space(1))) uint32_t*)g,
      (__attribute__((address_space(3))) uint32_t*)l,
      16, 0, 0);
}

/* -------- K0: copy feats -> out + sqnorm keys + weight conversion ------- */
__global__ __launch_bounds__(256) void k_cpnw(const float* __restrict__ feats,
                                              float* __restrict__ out,
                                              uint32_t* __restrict__ keys,
                                              const float* __restrict__ wq,
                                              const float* __restrict__ wo,
                                              uint16_t* __restrict__ wqb,
                                              uint16_t* __restrict__ wob){
  int bx = blockIdx.x;
  if (bx < 1024){
    int wv = threadIdx.x >> 6, lane = threadIdx.x & 63;
    int row0 = bx*16 + wv*4;
#pragma unroll
    for (int r = 0; r < 4; ++r){
      int row = row0 + r;
      float2 v = *(const float2*)(feats + row*CC + lane*2);
      *(float2*)(out + row*CC + lane*2) = v;
      float s = v.x*v.x + v.y*v.y;
      for (int m = 1; m < 64; m <<= 1) s += __shfl_xor(s, m);
      if (lane == 0) keys[row] = __float_as_uint(s);
    }
  } else {
    int i = (bx - 1024)*256 + threadIdx.x;   /* 0..65535 */
    if (i < 3*CC*CC) wqb[i] = f2bf(wq[i]);
    else { int j = i - 3*CC*CC; wob[j] = f2bf(wo[j]); }
  }
}

/* ---------------- K2: exact top-4096 selection per batch ---------------- */
/* Privatized histograms (R10-proven) + single-wave suffix scan: wave 0
   sums the 16 per-wave hists and does the 256-bin suffix scan entirely
   with shfl (no barriers) -> 3 barriers/pass instead of ~19. Unique-bin
   select: suffix(>b) < r <= suffix(>=b) has exactly one solution.       */
__global__ __launch_bounds__(1024) void k_select(const uint32_t* __restrict__ keys,
                                                 int* __restrict__ sel){
  __shared__ uint32_t ka[NPB];
  __shared__ uint32_t hist[16*257];
  __shared__ uint32_t sh_prefix, sh_r;
  __shared__ int wsum[17];
  int tid = threadIdx.x, batch = blockIdx.x;
  int wv16 = tid >> 6;
  for (int i = tid; i < NPB; i += 1024) ka[i] = keys[batch*NPB + i];
  if (tid == 0){ sh_prefix = 0u; sh_r = KTOK; }
  __syncthreads();
  for (int pass = 0; pass < 4; ++pass){
    int shift = 24 - 8*pass;
    for (int i = tid; i < 16*257; i += 1024) hist[i] = 0u;
    __syncthreads();
    uint32_t pref = sh_prefix;
    uint32_t r0   = sh_r;
    uint32_t mask = (pass == 0) ? 0u : (0xFFFFFFFFu << (shift + 8));
    uint32_t* myh = &hist[wv16*257];
    for (int e = 0; e < 8; ++e){
      uint32_t k = ka[tid*8 + e];
      if ((k & mask) == pref) atomicAdd(&myh[(k >> shift) & 255], 1u);
    }
    __syncthreads();
    if (tid < 64){
      int lane = tid;
      uint32_t h0v = 0, h1v = 0, h2v = 0, h3v = 0;
      int b0 = lane*4;
#pragma unroll
      for (int w = 0; w < 16; ++w){
        const uint32_t* hw = &hist[w*257 + b0];
        h0v += hw[0]; h1v += hw[1]; h2v += hw[2]; h3v += hw[3];
      }
      uint32_t s3 = h3v, s2 = h2v + s3, s1 = h1v + s2, s0 = h0v + s1;
      uint32_t incl = s0;                 /* lane total */
      for (int d = 1; d < 64; d <<= 1){
        uint32_t t = __shfl_down(incl, d);
        if (lane + d < 64) incl += t;
      }
      uint32_t exA = incl - s0;           /* sum of lanes above */
      uint32_t sfx[4] = {s0, s1, s2, s3};
      uint32_t hh[4]  = {h0v, h1v, h2v, h3v};
#pragma unroll
      for (int k = 0; k < 4; ++k){
        uint32_t inc_b = exA + sfx[k];
        uint32_t Sx    = inc_b - hh[k];
        if (Sx < r0 && inc_b >= r0){
          sh_prefix = pref | ((uint32_t)(b0 + k) << shift);
          sh_r = r0 - Sx;
        }
      }
    }
    __syncthreads();
  }
  uint32_t T = sh_prefix; int need = (int)sh_r;
  int lgt = 0, leq = 0;
  for (int e = 0; e < 8; ++e){
    uint32_t k = ka[tid*8 + e];
    lgt += (k > T); leq += (k == T);
  }
  int lane = tid & 63, wv = tid >> 6;
  int egt, tgt, eeq;
  {
    __syncthreads();
    int incl = lgt;
    for (int d = 1; d < 64; d <<= 1){ int t = __shfl_up(incl, d); if (lane >= d) incl += t; }
    if (lane == 63) wsum[wv] = incl;
    __syncthreads();
    if (tid == 0){ int run = 0; for (int w = 0; w < 16; ++w){ int t = wsum[w]; wsum[w] = run; run += t; } wsum[16] = run; }
    __syncthreads();
    egt = wsum[wv] + incl - lgt; tgt = wsum[16];
  }
  {
    __syncthreads();
    int incl = leq;
    for (int d = 1; d < 64; d <<= 1){ int t = __shfl_up(incl, d); if (lane >= d) incl += t; }
    if (lane == 63) wsum[wv] = incl;
    __syncthreads();
    if (tid == 0){ int run = 0; for (int w = 0; w < 16; ++w){ int t = wsum[w]; wsum[w] = run; run += t; } }
    __syncthreads();
    eeq = wsum[wv] + incl - leq;
  }
  int chi = tgt, gpos = egt, epos = eeq;
  for (int e = 0; e < 8; ++e){
    int i = tid*8 + e;
    uint32_t k = ka[i];
    if (k > T){ sel[batch*KTOK + (gpos++)] = batch*NPB + i; }
    else if (k == T){ if (epos < need) sel[batch*KTOK + chi + epos] = batch*NPB + i; epos++; }
  }
}

/* ------ K5: QKV projection GEMM, fused gather (8192x384x128) ------------ */
/* One block per 16-row tile: gathers its rows from feats via sel (fp32 ->
   bf16 A-frags in registers, RNE via v_cvt_pk), then loops all 6 col
   groups -> A read once (not 6x), no xab round-trip, no k_gather kernel.
   Q pre-scaled by log2(e)/sqrt(Dh).                                      */
__global__ __launch_bounds__(256) void k_qkv(const float* __restrict__ feats,
                                             const int* __restrict__ sel,
                                             const uint16_t* __restrict__ wqb,
                                             const float* __restrict__ bias,
                                             uint16_t* __restrict__ Qg,
                                             uint16_t* __restrict__ Kg,
                                             uint16_t* __restrict__ Vt){
  int wave = threadIdx.x >> 6, lane = threadIdx.x & 63;
  int l15 = lane & 15, g = lane >> 4;
  int rt = blockIdx.x;               /* 512 row tiles */
  int arow = rt*16 + l15;
  int grow = sel[arow];
  sh8 aF[4];
#pragma unroll
  for (int kk = 0; kk < 4; ++kk){
    const float* src = feats + grow*CC + kk*32 + g*8;
    float4 v0 = *(const float4*)(src);
    float4 v1 = *(const float4*)(src + 4);
    ux4 u;
    u.x = cvtpk1(v0.x, v0.y);
    u.y = cvtpk1(v0.z, v0.w);
    u.z = cvtpk1(v1.x, v1.y);
    u.w = cvtpk1(v1.z, v1.w);
    aF[kk] = *(sh8*)&u;
  }
  int tbase = rt*16;
  int b  = tbase >> 12;
  int q0 = (tbase & 4095) + g*4;     /* 4 consecutive within-batch slots */
#pragma unroll
  for (int cg = 0; cg < 6; ++cg){
    int bcol = (cg*4 + wave)*16 + l15;
    fx4 acc = {0.f,0.f,0.f,0.f};
#pragma unroll
    for (int kk = 0; kk < 4; ++kk){
      sh8 bF = *(const sh8*)(wqb + bcol*CC + kk*32 + g*8);
      acc = mfma32(aF[kk], bF, acc);
    }
    int j = bcol;
    float bj = bias[j];
    if (j < CC){
      int h = j >> 5, d = j & 31;
      uint16_t* p = Qg + ((b*HH + h)*KTOK + q0)*DH + d;
#pragma unroll
      for (int i = 0; i < 4; ++i) p[i*DH] = f2bf((acc[i] + bj) * K2C);
    } else if (j < 2*CC){
      int jj = j - CC; int h = jj >> 5, d = jj & 31;
      uint16_t* p = Kg + ((b*HH + h)*KTOK + q0)*DH + d;
#pragma unroll
      for (int i = 0; i < 4; ++i) p[i*DH] = f2bf(acc[i] + bj);
    } else {
      int jj = j - 2*CC; int h = jj >> 5, d = jj & 31;
      uint16_t* p = Vt + ((b*HH + h)*DH + d)*KTOK + q0;
      ux2 w; w.x = pk2(acc[0]+bj, acc[1]+bj); w.y = pk2(acc[2]+bj, acc[3]+bj);
      *(ux2*)p = w;
    }
  }
}

/* ---- K6: attention — block-shared staging, TK=64 (R15-proven) ---------- */
__global__ __launch_bounds__(512, 4) void k_attn(const uint16_t* __restrict__ Qg,
                                                 const uint16_t* __restrict__ Kg,
                                                 const uint16_t* __restrict__ Vtg,
                                                 uint16_t* __restrict__ O){
  __shared__ __align__(16) char lds[65536];
  int tid = threadIdx.x;
  int wv = tid >> 6, lane = tid & 63;
  int l31 = lane & 31, hi = lane >> 5;
  int seg = wv & 3, tq = wv >> 2;
  int bh = blockIdx.y;
  int qt = blockIdx.x;                 /* 64 q64-tiles per bh */
  const uint16_t* Qp = Qg  + bh*KTOK*DH;
  const uint16_t* Kp = Kg  + bh*KTOK*DH;
  const uint16_t* Vp = Vtg + bh*DH*KTOK;
  int q = qt*64 + tq*32 + l31;
  sh8 qF0 = *(const sh8*)(Qp + q*DH + hi*8);        /* B: col=q, k=dh 0..15  */
  sh8 qF1 = *(const sh8*)(Qp + q*DH + 16 + hi*8);   /* B: col=q, k=dh 16..31 */

  uint16_t* st = (uint16_t*)lds;   /* [2 buf][4 seg][K0|K1|V0|V1] 1024-elem blocks */
  int key0 = seg*1024;
  int r16 = lane >> 2;
  int sx  = ((lane & 3) ^ ((r16 >> 1) & 3)) * 8;   /* pre-swizzled source slot */

  /* prologue: chunk 0 -> buf0 */
  {
    if (wv < 4){
      const uint16_t* kg = Kp + key0*DH;
      uint16_t* d = st + seg*4096;
#pragma unroll
      for (int ks = 0; ks < 2; ++ks){
        gload_lds(kg + (ks*32 + r16)*DH + sx,      d + ks*1024 + 0);
        gload_lds(kg + (ks*32 + 16 + r16)*DH + sx, d + ks*1024 + 512);
      }
    } else {
      const uint16_t* vg = Vp + key0;
      uint16_t* d = st + seg*4096 + 2048;
#pragma unroll
      for (int ks = 0; ks < 2; ++ks){
        gload_lds(vg + r16*KTOK + ks*32 + sx,        d + ks*1024 + 0);
        gload_lds(vg + (16+r16)*KTOK + ks*32 + sx,   d + ks*1024 + 512);
      }
    }
  }
  asm volatile("s_waitcnt vmcnt(0)" ::: "memory");
  __syncthreads();

  fx16 acc = {0,0,0,0,0,0,0,0,0,0,0,0,0,0,0,0};
  const fx16 z16 = {0,0,0,0,0,0,0,0,0,0,0,0,0,0,0,0};
  float lsum = 0.f;
  int swz = (l31 >> 1) & 3;
  int koff0 = l31*32 + ((hi     ^ swz)*8);
  int koff1 = l31*32 + (((hi+2) ^ swz)*8);

  for (int t = 0; t < 16; ++t){
    int b = t & 1;
    if (t < 15){
      int nk = key0 + (t+1)*64;
      if (wv < 4){
        const uint16_t* kg = Kp + nk*DH;
        uint16_t* d = st + ((b^1)*4 + seg)*4096;
#pragma unroll
        for (int ks = 0; ks < 2; ++ks){
          gload_lds(kg + (ks*32 + r16)*DH + sx,      d + ks*1024 + 0);
          gload_lds(kg + (ks*32 + 16 + r16)*DH + sx, d + ks*1024 + 512);
        }
      } else {
        const uint16_t* vg = Vp + nk;
        uint16_t* d = st + ((b^1)*4 + seg)*4096 + 2048;
#pragma unroll
        for (int ks = 0; ks < 2; ++ks){
          gload_lds(vg + r16*KTOK + ks*32 + sx,        d + ks*1024 + 0);
          gload_lds(vg + (16+r16)*KTOK + ks*32 + sx,   d + ks*1024 + 512);
        }
      }
    }
    const uint16_t* base = st + (b*4 + seg)*4096;
#pragma unroll
    for (int ks = 0; ks < 2; ++ks){
      const uint16_t* bK = base + ks*1024;
      const uint16_t* bV = base + 2048 + ks*1024;
      sh8 kA0 = *(const sh8*)(bK + koff0);
      sh8 kA1 = *(const sh8*)(bK + koff1);
      fx16 S = mfma32x32(kA0, qF0, z16);
      S = mfma32x32(kA1, qF1, S);
      float e[16];
#pragma unroll
      for (int r = 0; r < 16; ++r) e[r] = fast_exp2(S[r]);
      float ls = 0.f;
#pragma unroll
      for (int r = 0; r < 16; ++r) ls += e[r];
      lsum += ls;
      uint32_t X0 = cvtpk1(e[0], e[1]),   X1 = cvtpk1(e[2], e[3]);
      uint32_t X2 = cvtpk1(e[4], e[5]),   X3 = cvtpk1(e[6], e[7]);
      uint32_t X4 = cvtpk1(e[8], e[9]),   X5 = cvtpk1(e[10], e[11]);
      uint32_t X6 = cvtpk1(e[12], e[13]), X7 = cvtpk1(e[14], e[15]);
      plswap(X0, X2); plswap(X1, X3);
      plswap(X4, X6); plswap(X5, X7);
      ux4 w0, w1;
      w0.x = X0; w0.y = X1; w0.z = X2; w0.w = X3;
      w1.x = X4; w1.y = X5; w1.z = X6; w1.w = X7;
      sh8 pa0 = *(sh8*)&w0;   /* A: row=q, k=keys 0..15 of sub-tile  */
      sh8 pa1 = *(sh8*)&w1;   /* A: row=q, k=keys 16..31 of sub-tile */
      sh8 vB0 = *(const sh8*)(bV + koff0);   /* B: col=dh, k=keys 0..15  */
      sh8 vB1 = *(const sh8*)(bV + koff1);   /* B: col=dh, k=keys 16..31 */
      acc = mfma32x32(pa0, vB0, acc);
      acc = mfma32x32(pa1, vB1, acc);
    }
    asm volatile("s_waitcnt vmcnt(0)" ::: "memory");
    __syncthreads();
  }

  /* combine 4 segments x 2 tiles; staging LDS reused (all past final barrier) */
  float* cmb = (float*)lds;                    /* [2 tq][4 seg][64][16] = 32KB */
  float* lwp = (float*)(lds + 32768);          /* [8][32]                      */
  float* ltr = (float*)(lds + 32768 + 1024);   /* [2][32]                      */
  lsum += __shfl_xor(lsum, 32);                /* seg-total l for this q       */
#pragma unroll
  for (int i = 0; i < 16; i += 4){
    fx4 p = {acc[i], acc[i+1], acc[i+2], acc[i+3]};
    *(fx4*)&cmb[((tq*4 + seg)*64 + lane)*16 + i] = p;
  }
  if (!hi) lwp[wv*32 + l31] = lsum;
  __syncthreads();
  if (seg == 0){   /* waves 0 (tile A) and 4 (tile B) */
#pragma unroll
    for (int s = 1; s < 4; ++s){
#pragma unroll
      for (int i = 0; i < 16; i += 4){
        fx4 p = *(const fx4*)&cmb[((tq*4 + s)*64 + lane)*16 + i];
        acc[i] += p.x; acc[i+1] += p.y; acc[i+2] += p.z; acc[i+3] += p.w;
      }
    }
    float lt = (lwp[(tq*4+0)*32 + l31] + lwp[(tq*4+1)*32 + l31])
             + (lwp[(tq*4+2)*32 + l31] + lwp[(tq*4+3)*32 + l31]);
    if (!hi) ltr[tq*32 + l31] = lt;
    fx4 La = *(const fx4*)&ltr[tq*32 + 4*hi];
    fx4 Lb = *(const fx4*)&ltr[tq*32 + 8 + 4*hi];
    fx4 Lc = *(const fx4*)&ltr[tq*32 + 16 + 4*hi];
    fx4 Ld = *(const fx4*)&ltr[tq*32 + 24 + 4*hi];
    fx4 Ra = {1.f/La.x, 1.f/La.y, 1.f/La.z, 1.f/La.w};
    fx4 Rb = {1.f/Lb.x, 1.f/Lb.y, 1.f/Lb.z, 1.f/Lb.w};
    fx4 Rc = {1.f/Lc.x, 1.f/Lc.y, 1.f/Lc.z, 1.f/Lc.w};
    fx4 Rd = {1.f/Ld.x, 1.f/Ld.y, 1.f/Ld.z, 1.f/Ld.w};
    int bb = bh >> 2, h = bh & 3;
    uint16_t* op = O + (bb*KTOK + qt*64 + tq*32)*CC + h*DH + l31;
#pragma unroll
    for (int r = 0; r < 16; ++r){
      int qd = (r&3) + 8*(r>>2) + 4*hi;
      float rv = (r<4) ? Ra[r&3] : (r<8) ? Rb[r&3] : (r<12) ? Rc[r&3] : Rd[r&3];
      op[qd*CC] = f2bf(acc[r] * rv);
    }
  }
}

/* ---------------- K7: out-proj + residual + LayerNorm + scatter --------- */
__global__ __launch_bounds__(256) void k_outln(const uint16_t* __restrict__ O,
                                               const uint16_t* __restrict__ wob,
                                               const float* __restrict__ bo,
                                               const float* __restrict__ feats,
                                               const int* __restrict__ sel,
                                               const float* __restrict__ lnw,
                                               const float* __restrict__ lnb,
                                               float* __restrict__ out){
  __shared__ float red[16][4][2];
  int wave = threadIdx.x >> 6, lane = threadIdx.x & 63;
  int l15 = lane & 15, g = lane >> 4;
  int rt = blockIdx.x;
  int arow = rt*16 + l15;
  int jA = wave*32 + l15, jB = jA + 16;
  fx4 accA = {0,0,0,0}, accB = {0,0,0,0};
#pragma unroll
  for (int kk = 0; kk < 4; ++kk){
    sh8 aF = *(const sh8*)(O   + arow*CC + kk*32 + g*8);
    sh8 b0 = *(const sh8*)(wob + jA*CC   + kk*32 + g*8);
    sh8 b1 = *(const sh8*)(wob + jB*CC   + kk*32 + g*8);
    accA = mfma32(aF, b0, accA);
    accB = mfma32(aF, b1, accB);
  }
  float bjA = bo[jA], bjB = bo[jB];
  float hA[4], hB[4]; int gl[4];
#pragma unroll
  for (int i = 0; i < 4; ++i){
    int r = rt*16 + g*4 + i;
    int grow = sel[r];
    gl[i] = grow;
    hA[i] = accA[i] + bjA + feats[grow*CC + jA];
    hB[i] = accB[i] + bjB + feats[grow*CC + jB];
  }
#pragma unroll
  for (int i = 0; i < 4; ++i){
    float s  = hA[i] + hB[i];
    float s2 = hA[i]*hA[i] + hB[i]*hB[i];
    for (int mk = 1; mk < 16; mk <<= 1){ s += __shfl_xor(s, mk); s2 += __shfl_xor(s2, mk); }
    if (l15 == 0){ red[g*4+i][wave][0] = s; red[g*4+i][wave][1] = s2; }
  }
  __syncthreads();
  float w0 = lnw[jA], w1 = lnw[jB], b0v = lnb[jA], b1v = lnb[jB];
#pragma unroll
  for (int i = 0; i < 4; ++i){
    int rl = g*4 + i;
    float tot  = red[rl][0][0] + red[rl][1][0] + red[rl][2][0] + red[rl][3][0];
    float tot2 = red[rl][0][1] + red[rl][1][1] + red[rl][2][1] + red[rl][3][1];
    float mu  = tot  * (1.f/128.f);
    float var = tot2 * (1.f/128.f) - mu*mu;
    float rs = rsqrtf(var + 1e-5f);
    out[gl[i]*CC + jA] = (hA[i]-mu)*rs*w0 + b0v;
    out[gl[i]*CC + jB] = (hB[i]-mu)*rs*w1 + b1v;
  }
}

extern "C" void kernel_launch(void* const* d_in, const int* in_sizes, int n_in,
                              void* d_out, int out_size, void* d_ws, size_t ws_size,
                              hipStream_t stream){
  const float* feats = (const float*)d_in[0];
  /* d_in[1] = batch_idx (int64) — contiguous equal groups, unused */
  const float* wqkv  = (const float*)d_in[2];
  const float* bqkv  = (const float*)d_in[3];
  const float* wout  = (const float*)d_in[4];
  const float* bout  = (const float*)d_in[5];
  const float* lnw   = (const float*)d_in[6];
  const float* lnb   = (const float*)d_in[7];
  float* out = (float*)d_out;
  char* ws = (char*)d_ws;

  uint32_t* keys = (uint32_t*)(ws + 0);        /* 64KB  */
  int*      sel  = (int*)     (ws + 65536);    /* 32KB  */
  uint16_t* wqb  = (uint16_t*)(ws + 98304);    /* 96KB  */
  uint16_t* wob  = (uint16_t*)(ws + 196608);   /* 32KB  */
  uint16_t* Qg   = (uint16_t*)(ws + 2326528);  /* 2MB   */
  uint16_t* Kg   = (uint16_t*)(ws + 4423680);  /* 2MB   */
  uint16_t* Vt   = (uint16_t*)(ws + 6520832);  /* 2MB   */
  uint16_t* O    = (uint16_t*)(ws + 8617984);  /* 2MB   */

  hipLaunchKernelGGL(k_cpnw,   dim3(1280),   dim3(256),  0, stream,
                     feats, out, keys, wqkv, wout, wqb, wob);
  hipLaunchKernelGGL(k_select, dim3(2),      dim3(1024), 0, stream, keys, sel);
  hipLaunchKernelGGL(k_qkv,    dim3(512),    dim3(256),  0, stream,
                     feats, sel, wqb, bqkv, Qg, Kg, Vt);
  hipLaunchKernelGGL(k_attn,   dim3(64,8),   dim3(512),  0, stream, Qg, Kg, Vt, O);
  hipLaunchKernelGGL(k_outln,  dim3(512),    dim3(256),  0, stream, O, wob, bout, feats, sel, lnw, lnb, out);
}

// Round 17
// 72.205 us; speedup vs baseline: 1.3979x; 1.0223x over previous
//
#include <hip/hip_runtime.h>
#include <hip/hip_bf16.h>
#include <stdint.h>

#define NPB 8192
#define CB 2
#define CC 128
#define HH 4
#define KTOK 4096
#define DH 32
#define NTOK (CB*KTOK)
#define K2C 0.25503402f  /* log2(e)/sqrt(32) */

typedef __attribute__((ext_vector_type(8))) short sh8;
typedef __attribute__((ext_vector_type(4))) float fx4;
typedef __attribute__((ext_vector_type(16))) float fx16;
typedef __attribute__((ext_vector_type(2))) uint32_t ux2;
typedef __attribute__((ext_vector_type(4))) uint32_t ux4;

__device__ inline uint16_t f2bf(float f){
  uint32_t x = __float_as_uint(f);
  return (uint16_t)((x + 0x7FFFu + ((x>>16)&1u)) >> 16);
}
__device__ inline uint32_t pk2(float a, float b){
  return (uint32_t)f2bf(a) | ((uint32_t)f2bf(b) << 16);
}
__device__ inline float fast_exp2(float x){
#if __has_builtin(__builtin_amdgcn_exp2f)
  return __builtin_amdgcn_exp2f(x);
#else
  return exp2f(x);
#endif
}
__device__ inline uint32_t cvtpk1(float a, float b){
  uint32_t u;
  asm("v_cvt_pk_bf16_f32 %0, %1, %2" : "=v"(u) : "v"(a), "v"(b));
  return u;
}
/* exchange halves across lane<32/lane>=32 (R13-proven) */
__device__ inline void plswap(uint32_t& a, uint32_t& b){
#if __has_builtin(__builtin_amdgcn_permlane32_swap)
  typedef __attribute__((ext_vector_type(2))) unsigned int u2;
  u2 r = __builtin_amdgcn_permlane32_swap(a, b, false, false);
  a = r.x; b = r.y;
#else
  int hi = (threadIdx.x & 63) >> 5;
  uint32_t t = __shfl_xor(hi ? a : b, 32);
  uint32_t na = hi ? t : a;
  uint32_t nb = hi ? b : t;
  a = na; b = nb;
#endif
}
__device__ inline fx4 mfma32(sh8 a, sh8 b, fx4 c){
  return __builtin_amdgcn_mfma_f32_16x16x32_bf16(a, b, c, 0, 0, 0);
}
__device__ inline fx16 mfma32x32(sh8 a, sh8 b, fx16 c){
  return __builtin_amdgcn_mfma_f32_32x32x16_bf16(a, b, c, 0, 0, 0);
}
__device__ inline void gload_lds(const uint16_t* g, uint16_t* l){
  __builtin_amdgcn_global_load_lds(
      (const __attribute__((address_space(1))) uint32_t*)g,
      (__attribute__((address_space(3))) uint32_t*)l,
      16, 0, 0);
}

/* -------- K0: copy feats -> out + sqnorm keys + weight conversion ------- */
__global__ __launch_bounds__(256) void k_cpnw(const float* __restrict__ feats,
                                              float* __restrict__ out,
                                              uint32_t* __restrict__ keys,
                                              const float* __restrict__ wq,
                                              const float* __restrict__ wo,
                                              uint16_t* __restrict__ wqb,
                                              uint16_t* __restrict__ wob){
  int bx = blockIdx.x;
  if (bx < 1024){
    int wv = threadIdx.x >> 6, lane = threadIdx.x & 63;
    int row0 = bx*16 + wv*4;
#pragma unroll
    for (int r = 0; r < 4; ++r){
      int row = row0 + r;
      float2 v = *(const float2*)(feats + row*CC + lane*2);
      *(float2*)(out + row*CC + lane*2) = v;
      float s = v.x*v.x + v.y*v.y;
      for (int m = 1; m < 64; m <<= 1) s += __shfl_xor(s, m);
      if (lane == 0) keys[row] = __float_as_uint(s);
    }
  } else {
    int i = (bx - 1024)*256 + threadIdx.x;   /* 0..65535 */
    if (i < 3*CC*CC) wqb[i] = f2bf(wq[i]);
    else { int j = i - 3*CC*CC; wob[j] = f2bf(wo[j]); }
  }
}

/* ---------------- K2: exact top-4096 selection per batch ---------------- */
__global__ __launch_bounds__(1024) void k_select(const uint32_t* __restrict__ keys,
                                                 int* __restrict__ sel){
  __shared__ uint32_t ka[NPB];
  __shared__ uint32_t hist[16*257];
  __shared__ uint32_t sh_prefix, sh_r;
  __shared__ int wsum[17];
  int tid = threadIdx.x, batch = blockIdx.x;
  int wv16 = tid >> 6;
  for (int i = tid; i < NPB; i += 1024) ka[i] = keys[batch*NPB + i];
  if (tid == 0){ sh_prefix = 0u; sh_r = KTOK; }
  __syncthreads();
  for (int pass = 0; pass < 4; ++pass){
    int shift = 24 - 8*pass;
    for (int i = tid; i < 16*257; i += 1024) hist[i] = 0u;
    __syncthreads();
    uint32_t pref = sh_prefix;
    uint32_t r0   = sh_r;
    uint32_t mask = (pass == 0) ? 0u : (0xFFFFFFFFu << (shift + 8));
    uint32_t* myh = &hist[wv16*257];
    for (int e = 0; e < 8; ++e){
      uint32_t k = ka[tid*8 + e];
      if ((k & mask) == pref) atomicAdd(&myh[(k >> shift) & 255], 1u);
    }
    __syncthreads();
    if (tid < 64){
      int lane = tid;
      uint32_t h0v = 0, h1v = 0, h2v = 0, h3v = 0;
      int b0 = lane*4;
#pragma unroll
      for (int w = 0; w < 16; ++w){
        const uint32_t* hw = &hist[w*257 + b0];
        h0v += hw[0]; h1v += hw[1]; h2v += hw[2]; h3v += hw[3];
      }
      uint32_t s3 = h3v, s2 = h2v + s3, s1 = h1v + s2, s0 = h0v + s1;
      uint32_t incl = s0;
      for (int d = 1; d < 64; d <<= 1){
        uint32_t t = __shfl_down(incl, d);
        if (lane + d < 64) incl += t;
      }
      uint32_t exA = incl - s0;
      uint32_t sfx[4] = {s0, s1, s2, s3};
      uint32_t hh[4]  = {h0v, h1v, h2v, h3v};
#pragma unroll
      for (int k = 0; k < 4; ++k){
        uint32_t inc_b = exA + sfx[k];
        uint32_t Sx    = inc_b - hh[k];
        if (Sx < r0 && inc_b >= r0){
          sh_prefix = pref | ((uint32_t)(b0 + k) << shift);
          sh_r = r0 - Sx;
        }
      }
    }
    __syncthreads();
  }
  uint32_t T = sh_prefix; int need = (int)sh_r;
  int lgt = 0, leq = 0;
  for (int e = 0; e < 8; ++e){
    uint32_t k = ka[tid*8 + e];
    lgt += (k > T); leq += (k == T);
  }
  int lane = tid & 63, wv = tid >> 6;
  int egt, tgt, eeq;
  {
    __syncthreads();
    int incl = lgt;
    for (int d = 1; d < 64; d <<= 1){ int t = __shfl_up(incl, d); if (lane >= d) incl += t; }
    if (lane == 63) wsum[wv] = incl;
    __syncthreads();
    if (tid == 0){ int run = 0; for (int w = 0; w < 16; ++w){ int t = wsum[w]; wsum[w] = run; run += t; } wsum[16] = run; }
    __syncthreads();
    egt = wsum[wv] + incl - lgt; tgt = wsum[16];
  }
  {
    __syncthreads();
    int incl = leq;
    for (int d = 1; d < 64; d <<= 1){ int t = __shfl_up(incl, d); if (lane >= d) incl += t; }
    if (lane == 63) wsum[wv] = incl;
    __syncthreads();
    if (tid == 0){ int run = 0; for (int w = 0; w < 16; ++w){ int t = wsum[w]; wsum[w] = run; run += t; } }
    __syncthreads();
    eeq = wsum[wv] + incl - leq;
  }
  int chi = tgt, gpos = egt, epos = eeq;
  for (int e = 0; e < 8; ++e){
    int i = tid*8 + e;
    uint32_t k = ka[i];
    if (k > T){ sel[batch*KTOK + (gpos++)] = batch*NPB + i; }
    else if (k == T){ if (epos < need) sel[batch*KTOK + chi + epos] = batch*NPB + i; epos++; }
  }
}

/* ------ K5: QKV projection GEMM, fused gather (8192x384x128) ------------ */
__global__ __launch_bounds__(256) void k_qkv(const float* __restrict__ feats,
                                             const int* __restrict__ sel,
                                             const uint16_t* __restrict__ wqb,
                                             const float* __restrict__ bias,
                                             uint16_t* __restrict__ Qg,
                                             uint16_t* __restrict__ Kg,
                                             uint16_t* __restrict__ Vt){
  int wave = threadIdx.x >> 6, lane = threadIdx.x & 63;
  int l15 = lane & 15, g = lane >> 4;
  int rt = blockIdx.x;               /* 512 row tiles */
  int arow = rt*16 + l15;
  int grow = sel[arow];
  sh8 aF[4];
#pragma unroll
  for (int kk = 0; kk < 4; ++kk){
    const float* src = feats + grow*CC + kk*32 + g*8;
    float4 v0 = *(const float4*)(src);
    float4 v1 = *(const float4*)(src + 4);
    ux4 u;
    u.x = cvtpk1(v0.x, v0.y);
    u.y = cvtpk1(v0.z, v0.w);
    u.z = cvtpk1(v1.x, v1.y);
    u.w = cvtpk1(v1.z, v1.w);
    aF[kk] = *(sh8*)&u;
  }
  int tbase = rt*16;
  int b  = tbase >> 12;
  int q0 = (tbase & 4095) + g*4;     /* 4 consecutive within-batch slots */
#pragma unroll
  for (int cg = 0; cg < 6; ++cg){
    int bcol = (cg*4 + wave)*16 + l15;
    fx4 acc = {0.f,0.f,0.f,0.f};
#pragma unroll
    for (int kk = 0; kk < 4; ++kk){
      sh8 bF = *(const sh8*)(wqb + bcol*CC + kk*32 + g*8);
      acc = mfma32(aF[kk], bF, acc);
    }
    int j = bcol;
    float bj = bias[j];
    if (j < CC){
      int h = j >> 5, d = j & 31;
      uint16_t* p = Qg + ((b*HH + h)*KTOK + q0)*DH + d;
#pragma unroll
      for (int i = 0; i < 4; ++i) p[i*DH] = f2bf((acc[i] + bj) * K2C);
    } else if (j < 2*CC){
      int jj = j - CC; int h = jj >> 5, d = jj & 31;
      uint16_t* p = Kg + ((b*HH + h)*KTOK + q0)*DH + d;
#pragma unroll
      for (int i = 0; i < 4; ++i) p[i*DH] = f2bf(acc[i] + bj);
    } else {
      int jj = j - 2*CC; int h = jj >> 5, d = jj & 31;
      uint16_t* p = Vt + ((b*HH + h)*DH + d)*KTOK + q0;
      ux2 w; w.x = pk2(acc[0]+bj, acc[1]+bj); w.y = pk2(acc[2]+bj, acc[3]+bj);
      *(ux2*)p = w;
    }
  }
}

/* ---- K6: attention — 128q blocks (16 waves), block-shared TK=64 staging  */
/* R15-proven template, block geometry widened: 16 waves = 4 q-tiles (tq)
   x 4 segments (seg). Staging per chunk done once per block (waves 0-3
   stage K for seg 0-3, waves 4-7 stage V, waves 8-15 compute-only) and
   serves 4 q-tiles -> staged bytes per bh HALVE vs R16. Per-wave math,
   swizzle, and the proven sync (stage(t+1) -> compute(t) -> vmcnt(0) ->
   syncthreads) byte-identical. Combine: 4 seg x 4 tq, cmb aliases the
   staging LDS after the loop's final barrier (R15-proven reuse).        */
__global__ __launch_bounds__(1024) void k_attn(const uint16_t* __restrict__ Qg,
                                               const uint16_t* __restrict__ Kg,
                                               const uint16_t* __restrict__ Vtg,
                                               uint16_t* __restrict__ O){
  __shared__ __align__(16) char lds[68096];
  int tid = threadIdx.x;
  int wv = tid >> 6, lane = tid & 63;
  int l31 = lane & 31, hi = lane >> 5;
  int seg = wv & 3, tq = wv >> 2;      /* seg 0..3, tq 0..3 */
  int bh = blockIdx.y;
  int qt = blockIdx.x;                 /* 32 q128-tiles per bh */
  const uint16_t* Qp = Qg  + bh*KTOK*DH;
  const uint16_t* Kp = Kg  + bh*KTOK*DH;
  const uint16_t* Vp = Vtg + bh*DH*KTOK;
  int q = qt*128 + tq*32 + l31;
  sh8 qF0 = *(const sh8*)(Qp + q*DH + hi*8);        /* B: col=q, k=dh 0..15  */
  sh8 qF1 = *(const sh8*)(Qp + q*DH + 16 + hi*8);   /* B: col=q, k=dh 16..31 */

  uint16_t* st = (uint16_t*)lds;   /* [2 buf][4 seg][K0|K1|V0|V1] 1024-elem blocks */
  int key0 = seg*1024;
  int r16 = lane >> 2;
  int sx  = ((lane & 3) ^ ((r16 >> 1) & 3)) * 8;   /* pre-swizzled source slot */
  int sseg = wv & 3;                   /* staging segment for waves 0-7 */
  int skey0 = sseg*1024;

  /* prologue: chunk 0 -> buf0 (waves 0-3: K, waves 4-7: V, 8-15: none) */
  if (wv < 4){
    const uint16_t* kg = Kp + skey0*DH;
    uint16_t* d = st + sseg*4096;
#pragma unroll
    for (int ks = 0; ks < 2; ++ks){
      gload_lds(kg + (ks*32 + r16)*DH + sx,      d + ks*1024 + 0);
      gload_lds(kg + (ks*32 + 16 + r16)*DH + sx, d + ks*1024 + 512);
    }
  } else if (wv < 8){
    const uint16_t* vg = Vp + skey0;
    uint16_t* d = st + sseg*4096 + 2048;
#pragma unroll
    for (int ks = 0; ks < 2; ++ks){
      gload_lds(vg + r16*KTOK + ks*32 + sx,        d + ks*1024 + 0);
      gload_lds(vg + (16+r16)*KTOK + ks*32 + sx,   d + ks*1024 + 512);
    }
  }
  asm volatile("s_waitcnt vmcnt(0)" ::: "memory");
  __syncthreads();

  fx16 acc = {0,0,0,0,0,0,0,0,0,0,0,0,0,0,0,0};
  const fx16 z16 = {0,0,0,0,0,0,0,0,0,0,0,0,0,0,0,0};
  float lsum = 0.f;
  int swz = (l31 >> 1) & 3;
  int koff0 = l31*32 + ((hi     ^ swz)*8);
  int koff1 = l31*32 + (((hi+2) ^ swz)*8);

  for (int t = 0; t < 16; ++t){
    int b = t & 1;
    if (t < 15){
      int nk = skey0 + (t+1)*64;
      if (wv < 4){
        const uint16_t* kg = Kp + nk*DH;
        uint16_t* d = st + ((b^1)*4 + sseg)*4096;
#pragma unroll
        for (int ks = 0; ks < 2; ++ks){
          gload_lds(kg + (ks*32 + r16)*DH + sx,      d + ks*1024 + 0);
          gload_lds(kg + (ks*32 + 16 + r16)*DH + sx, d + ks*1024 + 512);
        }
      } else if (wv < 8){
        const uint16_t* vg = Vp + nk;
        uint16_t* d = st + ((b^1)*4 + sseg)*4096 + 2048;
#pragma unroll
        for (int ks = 0; ks < 2; ++ks){
          gload_lds(vg + r16*KTOK + ks*32 + sx,        d + ks*1024 + 0);
          gload_lds(vg + (16+r16)*KTOK + ks*32 + sx,   d + ks*1024 + 512);
        }
      }
    }
    const uint16_t* base = st + (b*4 + seg)*4096;
#pragma unroll
    for (int ks = 0; ks < 2; ++ks){
      const uint16_t* bK = base + ks*1024;
      const uint16_t* bV = base + 2048 + ks*1024;
      sh8 kA0 = *(const sh8*)(bK + koff0);
      sh8 kA1 = *(const sh8*)(bK + koff1);
      fx16 S = mfma32x32(kA0, qF0, z16);
      S = mfma32x32(kA1, qF1, S);
      float e[16];
#pragma unroll
      for (int r = 0; r < 16; ++r) e[r] = fast_exp2(S[r]);
      float ls = 0.f;
#pragma unroll
      for (int r = 0; r < 16; ++r) ls += e[r];
      lsum += ls;
      uint32_t X0 = cvtpk1(e[0], e[1]),   X1 = cvtpk1(e[2], e[3]);
      uint32_t X2 = cvtpk1(e[4], e[5]),   X3 = cvtpk1(e[6], e[7]);
      uint32_t X4 = cvtpk1(e[8], e[9]),   X5 = cvtpk1(e[10], e[11]);
      uint32_t X6 = cvtpk1(e[12], e[13]), X7 = cvtpk1(e[14], e[15]);
      plswap(X0, X2); plswap(X1, X3);
      plswap(X4, X6); plswap(X5, X7);
      ux4 w0, w1;
      w0.x = X0; w0.y = X1; w0.z = X2; w0.w = X3;
      w1.x = X4; w1.y = X5; w1.z = X6; w1.w = X7;
      sh8 pa0 = *(sh8*)&w0;   /* A: row=q, k=keys 0..15 of sub-tile  */
      sh8 pa1 = *(sh8*)&w1;   /* A: row=q, k=keys 16..31 of sub-tile */
      sh8 vB0 = *(const sh8*)(bV + koff0);   /* B: col=dh, k=keys 0..15  */
      sh8 vB1 = *(const sh8*)(bV + koff1);   /* B: col=dh, k=keys 16..31 */
      acc = mfma32x32(pa0, vB0, acc);
      acc = mfma32x32(pa1, vB1, acc);
    }
    asm volatile("s_waitcnt vmcnt(0)" ::: "memory");
    __syncthreads();
  }

  /* combine 4 segments x 4 tiles; staging LDS reused (all past final barrier) */
  float* cmb = (float*)lds;                    /* [4 tq][4 seg][64][16] = 64KB */
  float* lwp = (float*)(lds + 65536);          /* [16][32] = 2KB               */
  float* ltr = (float*)(lds + 65536 + 2048);   /* [4][32]                      */
  lsum += __shfl_xor(lsum, 32);                /* seg-total l for this q       */
#pragma unroll
  for (int i = 0; i < 16; i += 4){
    fx4 p = {acc[i], acc[i+1], acc[i+2], acc[i+3]};
    *(fx4*)&cmb[((tq*4 + seg)*64 + lane)*16 + i] = p;
  }
  if (!hi) lwp[wv*32 + l31] = lsum;
  __syncthreads();
  if (seg == 0){   /* waves 0,4,8,12 -> tiles tq=0..3 */
#pragma unroll
    for (int s = 1; s < 4; ++s){
#pragma unroll
      for (int i = 0; i < 16; i += 4){
        fx4 p = *(const fx4*)&cmb[((tq*4 + s)*64 + lane)*16 + i];
        acc[i] += p.x; acc[i+1] += p.y; acc[i+2] += p.z; acc[i+3] += p.w;
      }
    }
    float lt = (lwp[(tq*4+0)*32 + l31] + lwp[(tq*4+1)*32 + l31])
             + (lwp[(tq*4+2)*32 + l31] + lwp[(tq*4+3)*32 + l31]);
    if (!hi) ltr[tq*32 + l31] = lt;
    fx4 La = *(const fx4*)&ltr[tq*32 + 4*hi];
    fx4 Lb = *(const fx4*)&ltr[tq*32 + 8 + 4*hi];
    fx4 Lc = *(const fx4*)&ltr[tq*32 + 16 + 4*hi];
    fx4 Ld = *(const fx4*)&ltr[tq*32 + 24 + 4*hi];
    fx4 Ra = {1.f/La.x, 1.f/La.y, 1.f/La.z, 1.f/La.w};
    fx4 Rb = {1.f/Lb.x, 1.f/Lb.y, 1.f/Lb.z, 1.f/Lb.w};
    fx4 Rc = {1.f/Lc.x, 1.f/Lc.y, 1.f/Lc.z, 1.f/Lc.w};
    fx4 Rd = {1.f/Ld.x, 1.f/Ld.y, 1.f/Ld.z, 1.f/Ld.w};
    int bb = bh >> 2, h = bh & 3;
    uint16_t* op = O + (bb*KTOK + qt*128 + tq*32)*CC + h*DH + l31;
#pragma unroll
    for (int r = 0; r < 16; ++r){
      int qd = (r&3) + 8*(r>>2) + 4*hi;
      float rv = (r<4) ? Ra[r&3] : (r<8) ? Rb[r&3] : (r<12) ? Rc[r&3] : Rd[r&3];
      op[qd*CC] = f2bf(acc[r] * rv);
    }
  }
}

/* ---------------- K7: out-proj + residual + LayerNorm + scatter --------- */
__global__ __launch_bounds__(256) void k_outln(const uint16_t* __restrict__ O,
                                               const uint16_t* __restrict__ wob,
                                               const float* __restrict__ bo,
                                               const float* __restrict__ feats,
                                               const int* __restrict__ sel,
                                               const float* __restrict__ lnw,
                                               const float* __restrict__ lnb,
                                               float* __restrict__ out){
  __shared__ float red[16][4][2];
  int wave = threadIdx.x >> 6, lane = threadIdx.x & 63;
  int l15 = lane & 15, g = lane >> 4;
  int rt = blockIdx.x;
  int arow = rt*16 + l15;
  int jA = wave*32 + l15, jB = jA + 16;
  fx4 accA = {0,0,0,0}, accB = {0,0,0,0};
#pragma unroll
  for (int kk = 0; kk < 4; ++kk){
    sh8 aF = *(const sh8*)(O   + arow*CC + kk*32 + g*8);
    sh8 b0 = *(const sh8*)(wob + jA*CC   + kk*32 + g*8);
    sh8 b1 = *(const sh8*)(wob + jB*CC   + kk*32 + g*8);
    accA = mfma32(aF, b0, accA);
    accB = mfma32(aF, b1, accB);
  }
  float bjA = bo[jA], bjB = bo[jB];
  float hA[4], hB[4]; int gl[4];
#pragma unroll
  for (int i = 0; i < 4; ++i){
    int r = rt*16 + g*4 + i;
    int grow = sel[r];
    gl[i] = grow;
    hA[i] = accA[i] + bjA + feats[grow*CC + jA];
    hB[i] = accB[i] + bjB + feats[grow*CC + jB];
  }
#pragma unroll
  for (int i = 0; i < 4; ++i){
    float s  = hA[i] + hB[i];
    float s2 = hA[i]*hA[i] + hB[i]*hB[i];
    for (int mk = 1; mk < 16; mk <<= 1){ s += __shfl_xor(s, mk); s2 += __shfl_xor(s2, mk); }
    if (l15 == 0){ red[g*4+i][wave][0] = s; red[g*4+i][wave][1] = s2; }
  }
  __syncthreads();
  float w0 = lnw[jA], w1 = lnw[jB], b0v = lnb[jA], b1v = lnb[jB];
#pragma unroll
  for (int i = 0; i < 4; ++i){
    int rl = g*4 + i;
    float tot  = red[rl][0][0] + red[rl][1][0] + red[rl][2][0] + red[rl][3][0];
    float tot2 = red[rl][0][1] + red[rl][1][1] + red[rl][2][1] + red[rl][3][1];
    float mu  = tot  * (1.f/128.f);
    float var = tot2 * (1.f/128.f) - mu*mu;
    float rs = rsqrtf(var + 1e-5f);
    out[gl[i]*CC + jA] = (hA[i]-mu)*rs*w0 + b0v;
    out[gl[i]*CC + jB] = (hB[i]-mu)*rs*w1 + b1v;
  }
}

extern "C" void kernel_launch(void* const* d_in, const int* in_sizes, int n_in,
                              void* d_out, int out_size, void* d_ws, size_t ws_size,
                              hipStream_t stream){
  const float* feats = (const float*)d_in[0];
  /* d_in[1] = batch_idx (int64) — contiguous equal groups, unused */
  const float* wqkv  = (const float*)d_in[2];
  const float* bqkv  = (const float*)d_in[3];
  const float* wout  = (const float*)d_in[4];
  const float* bout  = (const float*)d_in[5];
  const float* lnw   = (const float*)d_in[6];
  const float* lnb   = (const float*)d_in[7];
  float* out = (float*)d_out;
  char* ws = (char*)d_ws;

  uint32_t* keys = (uint32_t*)(ws + 0);        /* 64KB  */
  int*      sel  = (int*)     (ws + 65536);    /* 32KB  */
  uint16_t* wqb  = (uint16_t*)(ws + 98304);    /* 96KB  */
  uint16_t* wob  = (uint16_t*)(ws + 196608);   /* 32KB  */
  uint16_t* Qg   = (uint16_t*)(ws + 2326528);  /* 2MB   */
  uint16_t* Kg   = (uint16_t*)(ws + 4423680);  /* 2MB   */
  uint16_t* Vt   = (uint16_t*)(ws + 6520832);  /* 2MB   */
  uint16_t* O    = (uint16_t*)(ws + 8617984);  /* 2MB   */

  hipLaunchKernelGGL(k_cpnw,   dim3(1280),   dim3(256),  0, stream,
                     feats, out, keys, wqkv, wout, wqb, wob);
  hipLaunchKernelGGL(k_select, dim3(2),      dim3(1024), 0, stream, keys, sel);
  hipLaunchKernelGGL(k_qkv,    dim3(512),    dim3(256),  0, stream,
                     feats, sel, wqb, bqkv, Qg, Kg, Vt);
  hipLaunchKernelGGL(k_attn,   dim3(32,8),   dim3(1024), 0, stream, Qg, Kg, Vt, O);
  hipLaunchKernelGGL(k_outln,  dim3(512),    dim3(256),  0, stream, O, wob, bout, feats, sel, lnw, lnb, out);
}